// Round 1
// baseline (12168.586 us; speedup 1.0000x reference)
//
#include <hip/hip_runtime.h>
#include <cstdio>

#ifndef __has_builtin
#define __has_builtin(x) 0
#endif

// ---------------- problem constants ----------------
#define NB      256     // batch
#define NT      48      // timesteps
#define NS      512     // hidden / feature
#define NG3     1536    // 3*H
#define KAHEAD  4

#define NBLOCKS  256
#define NTHREADS 1024
#define NGRP     8      // groups (≈ one per XCD)
#define CPG      32     // blocks per group
#define RPG      32     // batch rows per group

// ---------------- workspace layout (float offsets) ----------------
#define WS_D      0            // [256][512]
#define WS_LH     131072       // [256][512]
#define WS_GH     262144       // [256][1536]
#define WS_X      655360       // [256][520] (513 used)
#define X_STRIDE  520
#define WS_WHHT   788480       // [512][1536]  W_hh transposed
#define WS_WG     1574912      // [513][1536]  W_ih transposed, gate-interleaved (j*3+gate)
#define WS_H1     2362880      // [256][256]
#define WS_H2     2428416      // [256][128]
#define WS_H3     2461184      // [256][64]
#define WS_BAR    2477568      // 16 uints
#define WS_FLOATS 2477600

// ---------------- LDS layout (byte offsets), total 152064 <= 160K ----------------
#define LDS_HID   0            // float  [48][512]
#define LDS_LSB   98304        // ushort [48][512] (bf16 ls)
#define LDS_LH    147456       // float  [512]
#define LDS_WO    149504       // float  [512]
#define LDS_E     151552       // float  [64]
#define LDS_ATT   151808       // float  [64]
#define LDS_BYTES 152064

// ---------------- helpers ----------------
__device__ __forceinline__ float frcp_(float x) {
#if __has_builtin(__builtin_amdgcn_rcpf)
    return __builtin_amdgcn_rcpf(x);
#else
    return 1.0f / x;
#endif
}
__device__ __forceinline__ float ftanh_(float x) {
    float e = __expf(2.0f * x);
    return 1.0f - 2.0f * frcp_(e + 1.0f);
}
__device__ __forceinline__ float fsig_(float x) {
    return frcp_(1.0f + __expf(-x));
}
__device__ __forceinline__ float lrelu_(float x) { return fmaxf(x, 0.01f * x); }
__device__ __forceinline__ unsigned short f2bf_(float x) {
    unsigned u = __float_as_uint(x);
    u += 0x7FFFu + ((u >> 16) & 1u);
    return (unsigned short)(u >> 16);
}
__device__ __forceinline__ float bf2f_(unsigned short b) {
    return __uint_as_float(((unsigned)b) << 16);
}

// Monotonic-counter sub-grid barrier (32 blocks of one group).
// Device-scope so correctness does not depend on block->XCD mapping.
__device__ __forceinline__ void group_barrier(unsigned* bar, unsigned* epoch) {
    __syncthreads();
    if (threadIdx.x == 0) {
        __threadfence();   // make this block's global writes visible device-wide
        *epoch += CPG;
        __hip_atomic_fetch_add(bar, 1u, __ATOMIC_ACQ_REL, __HIP_MEMORY_SCOPE_AGENT);
        unsigned target = *epoch;
        int guard = 0;
        while (__hip_atomic_load(bar, __ATOMIC_ACQUIRE, __HIP_MEMORY_SCOPE_AGENT) < target) {
#if __has_builtin(__builtin_amdgcn_s_sleep)
            __builtin_amdgcn_s_sleep(1);
#endif
            if (++guard > (1 << 20)) break;   // fail-safe: terminate instead of hang
        }
        __threadfence();   // discard possibly-stale cached data before consuming
    }
    __syncthreads();
}

// ---------------- prep: transposes + zeroing (plain launch) ----------------
__global__ void prep_kernel(const float* __restrict__ Whh,
                            const float* __restrict__ Wih,
                            float* __restrict__ ws) {
    long i = (long)blockIdx.x * blockDim.x + threadIdx.x;
    long stride = (long)gridDim.x * blockDim.x;
    // W_hh^T : whht[k*1536+m] = W_hh[m*512+k]
    for (long p = i; p < 786432; p += stride) {
        int k = (int)(p / 1536), m = (int)(p % 1536);
        ws[WS_WHHT + p] = Whh[m * 512 + k];
    }
    // W_ih^T gate-interleaved: wg[k*1536 + j*3 + g] = W_ih[(g*512+j)*513 + k]
    for (long p = i; p < 787968; p += stride) {
        int k = (int)(p / 1536), c = (int)(p % 1536);
        int j = c / 3, gg = c - 3 * j;
        ws[WS_WG + p] = Wih[(gg * 512 + j) * 513 + k];
    }
    for (long p = i; p < 131072; p += stride) ws[WS_D + p] = 0.0f;
    if (i < 16) ((unsigned*)(ws + WS_BAR))[i] = 0u;
}

// ---------------- stage A: lh = d@Wh + bh ; gh = d@W_hh^T + b_hh ----------------
// group rows RPG=32; per block 64 of 2048 output cols; 1024 thr -> 2 cols each
__device__ __forceinline__ void stageA(int g, int cix, int tid,
        const float* __restrict__ d_s,
        const float* __restrict__ Wh, const float* __restrict__ bh,
        const float* __restrict__ whht, const float* __restrict__ bhh,
        float* __restrict__ lh_w, float* __restrict__ gh_w) {
    const int r  = tid >> 5;                 // 0..31
    const int b  = g * RPG + r;
    const int n0 = cix * 64 + (tid & 31) * 2;   // 0..2047 (block-uniform side)
    const float* a = d_s + b * NS;
    const float* Bp; float* op; const float* bp; int ldb;
    if (n0 < NS) { Bp = Wh + n0;               op = lh_w + b * NS + n0;   bp = bh  + n0;        ldb = NS;  }
    else         { int m = n0 - NS; Bp = whht + m; op = gh_w + b * NG3 + m; bp = bhh + m;       ldb = NG3; }
    float acc0 = 0.0f, acc1 = 0.0f;
    #pragma unroll 2
    for (int k = 0; k < NS; k += 4) {
        float4 av = *(const float4*)(a + k);
        float2 q0 = *(const float2*)(Bp);
        float2 q1 = *(const float2*)(Bp + ldb);
        float2 q2 = *(const float2*)(Bp + 2 * ldb);
        float2 q3 = *(const float2*)(Bp + 3 * ldb);
        Bp += 4 * ldb;
        acc0 = fmaf(av.x, q0.x, acc0); acc1 = fmaf(av.x, q0.y, acc1);
        acc0 = fmaf(av.y, q1.x, acc0); acc1 = fmaf(av.y, q1.y, acc1);
        acc0 = fmaf(av.z, q2.x, acc0); acc1 = fmaf(av.z, q2.y, acc1);
        acc0 = fmaf(av.w, q3.x, acc0); acc1 = fmaf(av.w, q3.y, acc1);
    }
    op[0] = acc0 + bp[0];
    op[1] = acc1 + bp[1];
}

// ---------------- stage C: gi = x@W_ih^T + b_ih ; fused GRU gate epilogue ----------------
// per block 16 j-columns (x3 gates); 512 active threads
__device__ __forceinline__ void stageC(int g, int cix, int tid,
        const float* __restrict__ x_w, const float* __restrict__ wg,
        const float* __restrict__ b_ih, const float* __restrict__ gh_w,
        float* __restrict__ d_s) {
    if (tid >= 512) return;
    const int r = tid >> 4, j2 = tid & 15;
    const int b = g * RPG + r;
    const int j = cix * 16 + j2;
    const float* a  = x_w + b * X_STRIDE;
    const float* Bg = wg + j * 3;
    float a0 = 0.0f, a1 = 0.0f, a2 = 0.0f;
    #pragma unroll 4
    for (int k = 0; k < NS + 1; ++k) {      // K = 513 (x[512] = ally/out scalar)
        float av = a[k];
        a0 = fmaf(av, Bg[0], a0);
        a1 = fmaf(av, Bg[1], a1);
        a2 = fmaf(av, Bg[2], a2);
        Bg += NG3;
    }
    float ir = a0 + b_ih[j], iz = a1 + b_ih[NS + j], inn = a2 + b_ih[2 * NS + j];
    const float* ghp = gh_w + b * NG3;
    float hr = ghp[j], hz = ghp[NS + j], hn = ghp[2 * NS + j];
    float hprev = d_s[b * NS + j];
    float rg = fsig_(ir + hr);
    float zg = fsig_(iz + hz);
    float ng = ftanh_(inn + rg * hn);
    d_s[b * NS + j] = (1.0f - zg) * ng + zg * hprev;
}

// ---------------- main persistent cooperative kernel ----------------
__global__ void __launch_bounds__(NTHREADS, 4) fused_kernel(
        const float* __restrict__ hiddens, const float* __restrict__ allys,
        const float* __restrict__ Wh, const float* __restrict__ bh,
        const float* __restrict__ Ws, const float* __restrict__ bs,
        const float* __restrict__ Wo, const float* __restrict__ bo,
        const float* __restrict__ b_ih, const float* __restrict__ b_hh,
        const float* __restrict__ W1, const float* __restrict__ b1,
        const float* __restrict__ W2, const float* __restrict__ b2,
        const float* __restrict__ W3, const float* __restrict__ b3,
        const float* __restrict__ W4, const float* __restrict__ b4,
        float* __restrict__ ws, float* __restrict__ out) {
    const int tid = threadIdx.x;
    const int bid = blockIdx.x;
    const int g   = bid & (NGRP - 1);     // group (likely one XCD)
    const int cix = bid >> 3;             // 0..31 within group
    const int myb = g * RPG + cix;        // the batch row this block owns for attention

    float* d_s  = ws + WS_D;
    float* lh_w = ws + WS_LH;
    float* gh_w = ws + WS_GH;
    float* x_w  = ws + WS_X;
    float* whht = ws + WS_WHHT;
    float* wg   = ws + WS_WG;
    float* h1w  = ws + WS_H1;
    float* h2w  = ws + WS_H2;
    float* h3w  = ws + WS_H3;
    unsigned* bar = (unsigned*)(ws + WS_BAR) + g;
    unsigned epoch = 0;

    extern __shared__ char smem[];
    float*          hid  = (float*)(smem + LDS_HID);           // [48][512] fp32
    unsigned short* lsb  = (unsigned short*)(smem + LDS_LSB);  // [48][512] bf16
    float*          lh_s = (float*)(smem + LDS_LH);
    float*          wo_s = (float*)(smem + LDS_WO);
    float*          e_s  = (float*)(smem + LDS_E);
    float*          att_s= (float*)(smem + LDS_ATT);

    // ---- load hiddens[myb] into LDS (fp32) ----
    {
        const float4* hsrc = (const float4*)(hiddens + (long)myb * (NT * NS));
        float4* hdst = (float4*)hid;
        for (int i = tid; i < (NT * NS) / 4; i += NTHREADS) hdst[i] = hsrc[i];
        if (tid < NS) wo_s[tid] = Wo[tid];
    }
    __syncthreads();

    // ---- ls[myb] = hiddens[myb] @ Ws + bs, stored bf16 in LDS ----
    {
        const int s = tid & (NS - 1), half = tid >> 9;   // 512 s-lanes x 2 halves
        const int t0 = half * 24;
        float acc[24];
        #pragma unroll
        for (int q = 0; q < 24; ++q) acc[q] = 0.0f;
        #pragma unroll 2
        for (int k = 0; k < NS; k += 4) {
            float w0 = Ws[(k + 0) * NS + s];
            float w1 = Ws[(k + 1) * NS + s];
            float w2 = Ws[(k + 2) * NS + s];
            float w3 = Ws[(k + 3) * NS + s];
            #pragma unroll
            for (int q = 0; q < 24; ++q) {
                float4 h4 = *(const float4*)(hid + (t0 + q) * NS + k);
                acc[q] = fmaf(h4.x, w0, fmaf(h4.y, w1, fmaf(h4.z, w2, fmaf(h4.w, w3, acc[q]))));
            }
        }
        float bsv = bs[s];
        #pragma unroll
        for (int q = 0; q < 24; ++q) lsb[(t0 + q) * NS + s] = f2bf_(acc[q] + bsv);
    }
    __syncthreads();

    const float bo0 = bo[0];

    // ================= time scan =================
    for (int t = 0; t < NT; ++t) {
        stageA(g, cix, tid, d_s, Wh, bh, whht, b_hh, lh_w, gh_w);
        group_barrier(bar, &epoch);

        // ---- stage B: attention for row myb (all in LDS) ----
        if (tid < NS) lh_s[tid] = lh_w[myb * NS + tid];
        __syncthreads();
        {
            const int wv = tid >> 6, ln = tid & 63;
            for (int q = 0; q < 3; ++q) {
                const int tt = wv * 3 + q;
                float p = 0.0f;
                #pragma unroll
                for (int i2 = 0; i2 < 8; ++i2) {
                    int s = ln + i2 * 64;
                    p = fmaf(wo_s[s], ftanh_(lh_s[s] + bf2f_(lsb[tt * NS + s])), p);
                }
                #pragma unroll
                for (int off = 32; off >= 1; off >>= 1) p += __shfl_xor(p, off, 64);
                if (ln == 0) e_s[tt] = p + bo0;
            }
        }
        __syncthreads();
        if (tid < 64) {
            float v = (tid < NT) ? e_s[tid] : -1e30f;
            float m = v;
            #pragma unroll
            for (int off = 32; off >= 1; off >>= 1) m = fmaxf(m, __shfl_xor(m, off, 64));
            float ex = (tid < NT) ? __expf(v - m) : 0.0f;
            float ssum = ex;
            #pragma unroll
            for (int off = 32; off >= 1; off >>= 1) ssum += __shfl_xor(ssum, off, 64);
            if (tid < NT) att_s[tid] = ex * frcp_(ssum);
        }
        __syncthreads();
        if (tid < NS) {
            float c = 0.0f;
            #pragma unroll
            for (int tt = 0; tt < NT; ++tt) c = fmaf(att_s[tt], hid[tt * NS + tid], c);
            x_w[myb * X_STRIDE + tid] = c;
        }
        if (tid == 0) x_w[myb * X_STRIDE + NS] = allys[myb * NT + t];
        group_barrier(bar, &epoch);

        stageC(g, cix, tid, x_w, wg, b_ih, gh_w, d_s);
        group_barrier(bar, &epoch);
    }

    // ================= k_wk_ahead head =================
    for (int kk = 0; kk < KAHEAD; ++kk) {
        if (tid < 256) {   // M1: 512 -> 256
            int r = tid >> 3, n = cix * 8 + (tid & 7);
            int b = g * RPG + r;
            const float* a = d_s + b * NS;
            float acc = 0.0f;
            for (int k = 0; k < 512; ++k) acc = fmaf(a[k], W1[k * 256 + n], acc);
            h1w[b * 256 + n] = lrelu_(acc + b1[n]);
        }
        group_barrier(bar, &epoch);
        if (tid < 128) {   // M2: 256 -> 128
            int r = tid >> 2, n = cix * 4 + (tid & 3);
            int b = g * RPG + r;
            const float* a = h1w + b * 256;
            float acc = 0.0f;
            for (int k = 0; k < 256; ++k) acc = fmaf(a[k], W2[k * 128 + n], acc);
            h2w[b * 128 + n] = lrelu_(acc + b2[n]);
        }
        group_barrier(bar, &epoch);
        if (tid < 64) {    // M3: 128 -> 64
            int r = tid >> 1, n = cix * 2 + (tid & 1);
            int b = g * RPG + r;
            const float* a = h2w + b * 128;
            float acc = 0.0f;
            for (int k = 0; k < 128; ++k) acc = fmaf(a[k], W3[k * 64 + n], acc);
            h3w[b * 64 + n] = lrelu_(acc + b3[n]);
        }
        group_barrier(bar, &epoch);
        if (tid < 64) {    // M4: 64 -> 1 (block handles its own row)
            float p = h3w[myb * 64 + tid] * W4[tid];
            #pragma unroll
            for (int off = 32; off >= 1; off >>= 1) p += __shfl_xor(p, off, 64);
            if (tid == 0) {
                float o = lrelu_(p + b4[0]);
                out[myb * KAHEAD + kk] = o;
                x_w[myb * X_STRIDE + NS] = o;   // x = [c_last, out]
            }
        }
        group_barrier(bar, &epoch);
        if (kk < KAHEAD - 1) {
            stageA(g, cix, tid, d_s, Wh, bh, whht, b_hh, lh_w, gh_w);
            group_barrier(bar, &epoch);
            stageC(g, cix, tid, x_w, wg, b_ih, gh_w, d_s);
            group_barrier(bar, &epoch);
        }
    }
}

// ---------------- host ----------------
extern "C" void kernel_launch(void* const* d_in, const int* in_sizes, int n_in,
                              void* d_out, int out_size, void* d_ws, size_t ws_size,
                              hipStream_t stream) {
    const float* hiddens = (const float*)d_in[0];
    const float* allys   = (const float*)d_in[1];
    // d_in[2] = k_wk_ahead (int, ==4) — compile-time constant here
    const float* Wh   = (const float*)d_in[3];
    const float* bh   = (const float*)d_in[4];
    const float* Ws   = (const float*)d_in[5];
    const float* bs   = (const float*)d_in[6];
    const float* Wo   = (const float*)d_in[7];
    const float* bo   = (const float*)d_in[8];
    const float* W_ih = (const float*)d_in[9];
    const float* W_hh = (const float*)d_in[10];
    const float* b_ih = (const float*)d_in[11];
    const float* b_hh = (const float*)d_in[12];
    const float* W1 = (const float*)d_in[13];
    const float* b1 = (const float*)d_in[14];
    const float* W2 = (const float*)d_in[15];
    const float* b2 = (const float*)d_in[16];
    const float* W3 = (const float*)d_in[17];
    const float* b3 = (const float*)d_in[18];
    const float* W4 = (const float*)d_in[19];
    const float* b4 = (const float*)d_in[20];
    float* wsf = (float*)d_ws;
    float* outf = (float*)d_out;

    if (ws_size < (size_t)WS_FLOATS * sizeof(float)) {
        fprintf(stderr, "kernel_launch: workspace too small (%zu < %zu)\n",
                ws_size, (size_t)WS_FLOATS * sizeof(float));
        return;
    }

    prep_kernel<<<dim3(1024), dim3(256), 0, stream>>>(W_hh, W_ih, wsf);

    (void)hipFuncSetAttribute((const void*)fused_kernel,
                              hipFuncAttributeMaxDynamicSharedMemorySize, LDS_BYTES);

    void* args[] = { &hiddens, &allys, &Wh, &bh, &Ws, &bs, &Wo, &bo,
                     &b_ih, &b_hh, &W1, &b1, &W2, &b2, &W3, &b3, &W4, &b4,
                     &wsf, &outf };
    hipError_t e = hipLaunchCooperativeKernel((void*)fused_kernel,
                                              dim3(NBLOCKS), dim3(NTHREADS),
                                              args, LDS_BYTES, stream);
    if (e != hipSuccess) {
        // co-residency is structurally guaranteed anyway (256 blocks, 1 block/CU, 256 CUs)
        fprintf(stderr, "coop launch failed (%d); falling back to plain launch\n", (int)e);
        (void)hipGetLastError();
        fused_kernel<<<dim3(NBLOCKS), dim3(NTHREADS), LDS_BYTES, stream>>>(
            hiddens, allys, Wh, bh, Ws, bs, Wo, bo, b_ih, b_hh,
            W1, b1, W2, b2, W3, b3, W4, b4, wsf, outf);
    }
}

// Round 2
// 5269.626 us; speedup vs baseline: 2.3092x; 2.3092x over previous
//
#include <hip/hip_runtime.h>
#include <cstdio>

#ifndef __has_builtin
#define __has_builtin(x) 0
#endif

// ---------------- problem constants ----------------
#define NB      256
#define NT      48
#define NS      512
#define KAHEAD  4
#define NTHREADS 1024
#define NBLOCKS  256
#define GSIZE    32     // blocks per group == rows per group
#define XS       516    // x row stride (513 used)

// ---------------- workspace layout (float offsets) ----------------
#define WS_D     0            // [256][512]
#define WS_LHW   131072       // [256][512]
#define WS_X     262144       // [256][516]
#define WS_WHG4  394240       // [512][512][4]  W_hh^T gate-interleaved, padded
#define WS_WG4   1442816      // [513][512][4]  W_ih^T gate-interleaved, padded
#define WS_BAR   2493440      // 256 uints (8 groups x 32-uint stride)
#define WS_FLOATS 2493696

// ---------------- LDS layout (byte offsets) ----------------
#define L_BUF0   0            // float [32][516]  (d_all in A, x_all in C)  66048
#define L_LSB    66048        // ushort [48][512] bf16 ls                   49152
#define L_GHS    115200       // float [32][16][3]                           6144
#define L_LH     121344       // float [512]                                 2048
#define L_WO     123392       // float [512]                                 2048
#define L_E      125440       // float [64]                                   256
#define L_ATT    125696       // float [64]                                   256
#define L_CP     125952       // float [512]                                 2048
#define L_H1P    128000       // float [256][4]                              4096
#define L_H1S    132096       // float [256]                                 1024
#define L_H2P    133120       // float [128][4]                              2048
#define L_H2S    135168       // float [128]                                  512
#define L_H3P    135680       // float [64][4]                               1024
#define LDS_BYTES 136704

// ---------------- helpers ----------------
__device__ __forceinline__ float frcp_(float x) {
#if __has_builtin(__builtin_amdgcn_rcpf)
    return __builtin_amdgcn_rcpf(x);
#else
    return 1.0f / x;
#endif
}
__device__ __forceinline__ float ftanh_(float x) {
    float e = __expf(2.0f * x);
    return 1.0f - 2.0f * frcp_(e + 1.0f);
}
__device__ __forceinline__ float fsig_(float x) { return frcp_(1.0f + __expf(-x)); }
__device__ __forceinline__ float lrelu_(float x) { return fmaxf(x, 0.01f * x); }
__device__ __forceinline__ unsigned short f2bf_(float x) {
    unsigned u = __float_as_uint(x);
    u += 0x7FFFu + ((u >> 16) & 1u);
    return (unsigned short)(u >> 16);
}
__device__ __forceinline__ float bf2f_(unsigned short b) {
    return __uint_as_float(((unsigned)b) << 16);
}

// Coherent (IF$-level) data exchange: relaxed agent atomics. The compiler
// emits the sc0/sc1 bypass bits; crucially, relaxed ordering emits NO
// buffer_inv / wb — L2 keeps the (read-only) weights resident.
__device__ __forceinline__ float aload(const float* p) {
    return __hip_atomic_load(p, __ATOMIC_RELAXED, __HIP_MEMORY_SCOPE_AGENT);
}
__device__ __forceinline__ void astore(float* p, float v) {
    __hip_atomic_store(p, v, __ATOMIC_RELAXED, __HIP_MEMORY_SCOPE_AGENT);
}

// Group barrier: monotonic counter, relaxed atomics only. Ordering argument:
// __syncthreads() emits s_waitcnt vmcnt(0) before s_barrier, so every
// thread's coherent stores have completed at IF$ before tid0 signals.
__device__ __forceinline__ void gbar(unsigned* bar, unsigned* epoch) {
    __syncthreads();
    if (threadIdx.x == 0) {
        *epoch += GSIZE;
        __hip_atomic_fetch_add(bar, 1u, __ATOMIC_RELAXED, __HIP_MEMORY_SCOPE_AGENT);
        unsigned target = *epoch;
        int guard = 0;
        while (__hip_atomic_load(bar, __ATOMIC_RELAXED, __HIP_MEMORY_SCOPE_AGENT) < target) {
#if __has_builtin(__builtin_amdgcn_s_sleep)
            __builtin_amdgcn_s_sleep(2);
#endif
            if (++guard > (1 << 20)) break;   // fail-safe: surface as wrong answer, not hang
        }
    }
    __syncthreads();
}

// ---------------- prep: weight transposes + zeroing ----------------
__global__ void prep_kernel(const float* __restrict__ Whh,
                            const float* __restrict__ Wih,
                            float* __restrict__ ws) {
    long i = (long)blockIdx.x * blockDim.x + threadIdx.x;
    long stride = (long)gridDim.x * blockDim.x;
    // whg4[(k*512+j)*4+g] = W_hh[(g*512+j)*512+k]   (coalesced reads over k)
    for (long p = i; p < 262144; p += stride) {
        int j = (int)(p >> 9), k = (int)(p & 511);
        long base = WS_WHG4 + ((long)(k * 512 + j) << 2);
        ws[base + 0] = Whh[(long)j * 512 + k];
        ws[base + 1] = Whh[(long)(512 + j) * 512 + k];
        ws[base + 2] = Whh[(long)(1024 + j) * 512 + k];
        ws[base + 3] = 0.0f;
    }
    // wg4[(k*512+j)*4+g] = W_ih[(g*512+j)*513+k], k<513
    for (long p = i; p < 262144; p += stride) {
        int j = (int)(p >> 9), k = (int)(p & 511);
        long base = WS_WG4 + ((long)(k * 512 + j) << 2);
        ws[base + 0] = Wih[(long)j * 513 + k];
        ws[base + 1] = Wih[(long)(512 + j) * 513 + k];
        ws[base + 2] = Wih[(long)(1024 + j) * 513 + k];
        ws[base + 3] = 0.0f;
    }
    for (long p = i; p < 512; p += stride) {           // k == 512 row of wg4
        int j = (int)p;
        long base = WS_WG4 + ((long)(512 * 512 + j) << 2);
        ws[base + 0] = Wih[(long)j * 513 + 512];
        ws[base + 1] = Wih[(long)(512 + j) * 513 + 512];
        ws[base + 2] = Wih[(long)(1024 + j) * 513 + 512];
        ws[base + 3] = 0.0f;
    }
    for (long p = i; p < 131072; p += stride) ws[WS_D + p] = 0.0f;
    if (i < 256) ((unsigned*)(ws + WS_BAR))[i] = 0u;
}

// ---------------- main persistent cooperative kernel ----------------
__global__ void __launch_bounds__(NTHREADS, 4) fused_kernel(
        const float* __restrict__ hiddens, const float* __restrict__ allys,
        const float* __restrict__ Wh, const float* __restrict__ bh,
        const float* __restrict__ Ws, const float* __restrict__ bs,
        const float* __restrict__ Wo, const float* __restrict__ bo,
        const float* __restrict__ b_ih, const float* __restrict__ b_hh,
        const float* __restrict__ W1, const float* __restrict__ b1,
        const float* __restrict__ W2, const float* __restrict__ b2,
        const float* __restrict__ W3, const float* __restrict__ b3,
        const float* __restrict__ W4, const float* __restrict__ b4,
        float* __restrict__ ws, float* __restrict__ out) {
    const int tid = threadIdx.x;
    const int bid = blockIdx.x;
    const int g   = bid >> 5;          // group 0..7
    const int cix = bid & 31;          // slice in group; cix&7 ~ XCD-aligned across groups
    const int myb = bid;               // the batch row this block owns

    float* dw    = ws + WS_D;
    float* lhw   = ws + WS_LHW;
    float* xw    = ws + WS_X;
    const float* whg4 = ws + WS_WHG4;
    const float* wg4  = ws + WS_WG4;
    unsigned* bar = (unsigned*)(ws + WS_BAR) + g * 32;
    unsigned epoch = 0;

    extern __shared__ char smem[];
    float*          buf0  = (float*)(smem + L_BUF0);
    unsigned short* lsb   = (unsigned short*)(smem + L_LSB);
    float*          gh_s  = (float*)(smem + L_GHS);
    float*          lh_s  = (float*)(smem + L_LH);
    float*          wo_s  = (float*)(smem + L_WO);
    float*          e_s   = (float*)(smem + L_E);
    float*          att_s = (float*)(smem + L_ATT);
    float*          cp_s  = (float*)(smem + L_CP);
    float*          h1p   = (float*)(smem + L_H1P);
    float*          h1s   = (float*)(smem + L_H1S);
    float*          h2p   = (float*)(smem + L_H2P);
    float*          h2s   = (float*)(smem + L_H2S);
    float*          h3p   = (float*)(smem + L_H3P);

    const int lane = tid & 31, r32 = tid >> 5;    // r32: row within group
    const int jj = lane & 15, kh = lane >> 4;     // j within slice, K-half
    const int jg = cix * 16 + jj;                 // global j (0..511)
    const int sS = tid & 511, th = tid >> 9;      // s-lane, t-half

    float hreg[24];                               // hiddens[myb][th*24+q][sS]

    if (tid < NS) wo_s[tid] = Wo[tid];

    // ==== startup: ls = hiddens[myb] @ Ws + bs (bf16 into LDS), hid -> regs ====
    for (int ch = 0; ch < 2; ++ch) {
        __syncthreads();
        {   // stage 24 t-rows of hiddens[myb] into buf0 (tight [24][512], linear copy)
            const float* src = hiddens + ((long)myb * NT + ch * 24) * NS;
            int idx = tid * 12;
            const float4* s4 = (const float4*)(src + idx);
            float4* d4 = (float4*)(buf0 + idx);
            d4[0] = s4[0]; d4[1] = s4[1]; d4[2] = s4[2];
        }
        __syncthreads();
        if (th == ch) {
            #pragma unroll
            for (int q = 0; q < 24; ++q) hreg[q] = buf0[q * 512 + sS];
        }
        {   // ls for 12 global-t rows per thread
            const int tl = th * 12;               // local row base in chunk
            float acc[12];
            #pragma unroll
            for (int q = 0; q < 12; ++q) acc[q] = 0.0f;
            for (int k = 0; k < NS; k += 4) {
                float w0 = Ws[(k + 0) * NS + sS];
                float w1 = Ws[(k + 1) * NS + sS];
                float w2 = Ws[(k + 2) * NS + sS];
                float w3 = Ws[(k + 3) * NS + sS];
                #pragma unroll
                for (int q = 0; q < 12; ++q) {
                    float4 h4 = *(const float4*)(buf0 + (tl + q) * 512 + k);
                    acc[q] = fmaf(h4.x, w0, fmaf(h4.y, w1, fmaf(h4.z, w2, fmaf(h4.w, w3, acc[q]))));
                }
            }
            float bsv = bs[sS];
            #pragma unroll
            for (int q = 0; q < 12; ++q)
                lsb[(ch * 24 + tl + q) * NS + sS] = f2bf_(acc[q] + bsv);
        }
    }
    __syncthreads();

    const float bo0 = bo[0];

    // ================= time scan: 3 phases, 3 group barriers per step =================
    for (int t = 0; t < NT; ++t) {
        // ---- A: stage d_all; gh (block-local j-slice); lh column-slice ----
        {
            int idx = tid * 16, rr = idx >> 9, c = idx & 511;
            const float* src = dw + ((long)(g * 32 + rr) << 9) + c;
            float* dst = buf0 + rr * 516 + c;
            float v[16];
            #pragma unroll
            for (int i = 0; i < 16; ++i) v[i] = aload(src + i);
            #pragma unroll
            for (int i = 0; i < 16; ++i) dst[i] = v[i];
        }
        __syncthreads();
        {   // gh = d @ W_hh^T + b_hh   (own 16 j, all 32 rows) -> gh_s
            const float* wp = whg4 + ((long)(kh * 256) * 512 + jg) * 4;
            const float* av = buf0 + r32 * 516 + kh * 256;
            float a0 = 0.f, a1 = 0.f, a2 = 0.f;
            #pragma unroll 4
            for (int k2 = 0; k2 < 256; ++k2) {
                float a = av[k2];
                float4 w = *(const float4*)wp; wp += 2048;
                a0 = fmaf(a, w.x, a0); a1 = fmaf(a, w.y, a1); a2 = fmaf(a, w.z, a2);
            }
            a0 += __shfl_xor(a0, 16, 64);
            a1 += __shfl_xor(a1, 16, 64);
            a2 += __shfl_xor(a2, 16, 64);
            if (kh == 0) {
                float* gp = gh_s + (r32 * 16 + jj) * 3;
                gp[0] = a0 + b_hh[jg];
                gp[1] = a1 + b_hh[NS + jg];
                gp[2] = a2 + b_hh[2 * NS + jg];
            }
        }
        {   // lh column-slice: lh[b][jg] for all 32 rows -> exchange
            const float* wp = Wh + (long)(kh * 256) * 512 + jg;
            const float* av = buf0 + r32 * 516 + kh * 256;
            float acc = 0.f;
            #pragma unroll 4
            for (int k2 = 0; k2 < 256; ++k2) { acc = fmaf(av[k2], wp[0], acc); wp += 512; }
            acc += __shfl_xor(acc, 16, 64);
            if (kh == 0) astore(lhw + ((long)(g * 32 + r32) << 9) + jg, acc + bh[jg]);
        }
        gbar(bar, &epoch);

        // ---- B: attention for own row ----
        if (tid < NS) lh_s[tid] = aload(lhw + ((long)myb << 9) + tid);
        if (tid == 0) astore(xw + (long)myb * XS + NS, allys[myb * NT + t]);
        __syncthreads();
        {   // e[t'] = sum_s wo[s]*tanh(lh[s]+ls[t'][s]) + bo
            const int wv = tid >> 6, ln = tid & 63;
            for (int q = 0; q < 3; ++q) {
                const int tt = wv * 3 + q;
                float p = 0.f;
                #pragma unroll
                for (int i2 = 0; i2 < 8; ++i2) {
                    int s = ln + (i2 << 6);
                    p = fmaf(wo_s[s], ftanh_(lh_s[s] + bf2f_(lsb[tt * NS + s])), p);
                }
                #pragma unroll
                for (int off = 32; off >= 1; off >>= 1) p += __shfl_xor(p, off, 64);
                if (ln == 0) e_s[tt] = p + bo0;
            }
        }
        __syncthreads();
        if (tid < 64) {
            float v = (tid < NT) ? e_s[tid] : -1e30f;
            float m = v;
            #pragma unroll
            for (int off = 32; off >= 1; off >>= 1) m = fmaxf(m, __shfl_xor(m, off, 64));
            float ex = (tid < NT) ? __expf(v - m) : 0.0f;
            float ssum = ex;
            #pragma unroll
            for (int off = 32; off >= 1; off >>= 1) ssum += __shfl_xor(ssum, off, 64);
            if (tid < NT) att_s[tid] = ex * frcp_(ssum);
        }
        __syncthreads();
        {   // c[s] = sum_t att[t]*hid[t][s]  (hid in registers)
            float p = 0.f;
            #pragma unroll
            for (int q = 0; q < 24; ++q) p = fmaf(att_s[th * 24 + q], hreg[q], p);
            if (th == 0) cp_s[sS] = p;
            __syncthreads();
            if (th == 1) astore(xw + (long)myb * XS + sS, p + cp_s[sS]);
        }
        gbar(bar, &epoch);

        // ---- C: gi = x @ W_ih^T; GRU gates; write d ----
        float hprev = 0.f;
        if (kh == 0) hprev = buf0[r32 * 516 + jg];   // d_all still resident
        __syncthreads();
        {   // stage x_all into buf0
            int idx = tid * 16, rr = idx >> 9, c = idx & 511;
            const float* src = xw + (long)(g * 32 + rr) * XS + c;
            float* dst = buf0 + rr * 516 + c;
            float v[16];
            #pragma unroll
            for (int i = 0; i < 16; ++i) v[i] = aload(src + i);
            #pragma unroll
            for (int i = 0; i < 16; ++i) dst[i] = v[i];
            if (tid < 32) buf0[tid * 516 + 512] = aload(xw + (long)(g * 32 + tid) * XS + 512);
        }
        __syncthreads();
        {
            const float* wp = wg4 + ((long)(kh * 256) * 512 + jg) * 4;
            const float* av = buf0 + r32 * 516 + kh * 256;
            const int kn = kh ? 257 : 256;   // kh1 covers k=256..512 inclusive
            float c0 = 0.f, c1 = 0.f, c2 = 0.f;
            #pragma unroll 4
            for (int k2 = 0; k2 < kn; ++k2) {
                float a = av[k2];
                float4 w = *(const float4*)wp; wp += 2048;
                c0 = fmaf(a, w.x, c0); c1 = fmaf(a, w.y, c1); c2 = fmaf(a, w.z, c2);
            }
            c0 += __shfl_xor(c0, 16, 64);
            c1 += __shfl_xor(c1, 16, 64);
            c2 += __shfl_xor(c2, 16, 64);
            if (kh == 0) {
                const float* gp = gh_s + (r32 * 16 + jj) * 3;
                float ir = c0 + b_ih[jg], iz = c1 + b_ih[NS + jg], inn = c2 + b_ih[2 * NS + jg];
                float rg = fsig_(ir + gp[0]);
                float zg = fsig_(iz + gp[1]);
                float ng = ftanh_(inn + rg * gp[2]);
                astore(dw + ((long)(g * 32 + r32) << 9) + jg, (1.f - zg) * ng + zg * hprev);
            }
        }
        gbar(bar, &epoch);
    }

    // ================= k_wk_ahead head (MLP local to own row) =================
    for (int kk = 0; kk < KAHEAD; ++kk) {
        if (tid < NS) lh_s[tid] = aload(dw + ((long)myb << 9) + tid);   // own d row
        __syncthreads();
        {   // M1: 512 -> 256
            int n = tid & 255, q4 = tid >> 8;
            const float* av = lh_s + q4 * 128;
            const float* wp = W1 + (long)(q4 * 128) * 256 + n;
            float acc = 0.f;
            #pragma unroll 4
            for (int k2 = 0; k2 < 128; ++k2) { acc = fmaf(av[k2], wp[0], acc); wp += 256; }
            h1p[n * 4 + q4] = acc;
        }
        __syncthreads();
        if (tid < 256) {
            float v = h1p[tid * 4] + h1p[tid * 4 + 1] + h1p[tid * 4 + 2] + h1p[tid * 4 + 3];
            h1s[tid] = lrelu_(v + b1[tid]);
        }
        __syncthreads();
        if (tid < 512) {   // M2: 256 -> 128
            int n = tid & 127, q4 = tid >> 7;
            const float* av = h1s + q4 * 64;
            const float* wp = W2 + (long)(q4 * 64) * 128 + n;
            float acc = 0.f;
            #pragma unroll 4
            for (int k2 = 0; k2 < 64; ++k2) { acc = fmaf(av[k2], wp[0], acc); wp += 128; }
            h2p[n * 4 + q4] = acc;
        }
        __syncthreads();
        if (tid < 128) {
            float v = h2p[tid * 4] + h2p[tid * 4 + 1] + h2p[tid * 4 + 2] + h2p[tid * 4 + 3];
            h2s[tid] = lrelu_(v + b2[tid]);
        }
        __syncthreads();
        if (tid < 256) {   // M3: 128 -> 64
            int n = tid & 63, q4 = tid >> 6;
            const float* av = h2s + q4 * 32;
            const float* wp = W3 + (long)(q4 * 32) * 64 + n;
            float acc = 0.f;
            #pragma unroll 4
            for (int k2 = 0; k2 < 32; ++k2) { acc = fmaf(av[k2], wp[0], acc); wp += 64; }
            h3p[n * 4 + q4] = acc;
        }
        __syncthreads();
        if (tid < 64) {    // M3 epilogue + M4: 64 -> 1
            float v = h3p[tid * 4] + h3p[tid * 4 + 1] + h3p[tid * 4 + 2] + h3p[tid * 4 + 3];
            float h3v = lrelu_(v + b3[tid]);
            float p = h3v * W4[tid];
            #pragma unroll
            for (int off = 32; off >= 1; off >>= 1) p += __shfl_xor(p, off, 64);
            if (tid == 0) {
                float o = lrelu_(p + b4[0]);
                out[myb * KAHEAD + kk] = o;
                astore(xw + (long)myb * XS + NS, o);   // x = [c_last, out]
            }
        }
        if (kk < KAHEAD - 1) {
            gbar(bar, &epoch);   // out scalars visible group-wide
            // ---- folded A+C head phase (no attention) ----
            {
                int idx = tid * 16, rr = idx >> 9, c = idx & 511;
                const float* src = dw + ((long)(g * 32 + rr) << 9) + c;
                float* dst = buf0 + rr * 516 + c;
                float v[16];
                #pragma unroll
                for (int i = 0; i < 16; ++i) v[i] = aload(src + i);
                #pragma unroll
                for (int i = 0; i < 16; ++i) dst[i] = v[i];
            }
            __syncthreads();
            {   // gh
                const float* wp = whg4 + ((long)(kh * 256) * 512 + jg) * 4;
                const float* av = buf0 + r32 * 516 + kh * 256;
                float a0 = 0.f, a1 = 0.f, a2 = 0.f;
                #pragma unroll 4
                for (int k2 = 0; k2 < 256; ++k2) {
                    float a = av[k2];
                    float4 w = *(const float4*)wp; wp += 2048;
                    a0 = fmaf(a, w.x, a0); a1 = fmaf(a, w.y, a1); a2 = fmaf(a, w.z, a2);
                }
                a0 += __shfl_xor(a0, 16, 64);
                a1 += __shfl_xor(a1, 16, 64);
                a2 += __shfl_xor(a2, 16, 64);
                if (kh == 0) {
                    float* gp = gh_s + (r32 * 16 + jj) * 3;
                    gp[0] = a0 + b_hh[jg];
                    gp[1] = a1 + b_hh[NS + jg];
                    gp[2] = a2 + b_hh[2 * NS + jg];
                }
            }
            float hprev = 0.f;
            if (kh == 0) hprev = buf0[r32 * 516 + jg];
            __syncthreads();
            {   // stage x_all
                int idx = tid * 16, rr = idx >> 9, c = idx & 511;
                const float* src = xw + (long)(g * 32 + rr) * XS + c;
                float* dst = buf0 + rr * 516 + c;
                float v[16];
                #pragma unroll
                for (int i = 0; i < 16; ++i) v[i] = aload(src + i);
                #pragma unroll
                for (int i = 0; i < 16; ++i) dst[i] = v[i];
                if (tid < 32) buf0[tid * 516 + 512] = aload(xw + (long)(g * 32 + tid) * XS + 512);
            }
            __syncthreads();
            {   // gi + gates
                const float* wp = wg4 + ((long)(kh * 256) * 512 + jg) * 4;
                const float* av = buf0 + r32 * 516 + kh * 256;
                const int kn = kh ? 257 : 256;
                float c0 = 0.f, c1 = 0.f, c2 = 0.f;
                #pragma unroll 4
                for (int k2 = 0; k2 < kn; ++k2) {
                    float a = av[k2];
                    float4 w = *(const float4*)wp; wp += 2048;
                    c0 = fmaf(a, w.x, c0); c1 = fmaf(a, w.y, c1); c2 = fmaf(a, w.z, c2);
                }
                c0 += __shfl_xor(c0, 16, 64);
                c1 += __shfl_xor(c1, 16, 64);
                c2 += __shfl_xor(c2, 16, 64);
                if (kh == 0) {
                    const float* gp = gh_s + (r32 * 16 + jj) * 3;
                    float ir = c0 + b_ih[jg], iz = c1 + b_ih[NS + jg], inn = c2 + b_ih[2 * NS + jg];
                    float rg = fsig_(ir + gp[0]);
                    float zg = fsig_(iz + gp[1]);
                    float ng = ftanh_(inn + rg * gp[2]);
                    astore(dw + ((long)(g * 32 + r32) << 9) + jg, (1.f - zg) * ng + zg * hprev);
                }
            }
            gbar(bar, &epoch);
        }
    }
}

// ---------------- host ----------------
extern "C" void kernel_launch(void* const* d_in, const int* in_sizes, int n_in,
                              void* d_out, int out_size, void* d_ws, size_t ws_size,
                              hipStream_t stream) {
    const float* hiddens = (const float*)d_in[0];
    const float* allys   = (const float*)d_in[1];
    const float* Wh   = (const float*)d_in[3];
    const float* bh   = (const float*)d_in[4];
    const float* Ws   = (const float*)d_in[5];
    const float* bs   = (const float*)d_in[6];
    const float* Wo   = (const float*)d_in[7];
    const float* bo   = (const float*)d_in[8];
    const float* W_ih = (const float*)d_in[9];
    const float* W_hh = (const float*)d_in[10];
    const float* b_ih = (const float*)d_in[11];
    const float* b_hh = (const float*)d_in[12];
    const float* W1 = (const float*)d_in[13];
    const float* b1 = (const float*)d_in[14];
    const float* W2 = (const float*)d_in[15];
    const float* b2 = (const float*)d_in[16];
    const float* W3 = (const float*)d_in[17];
    const float* b3 = (const float*)d_in[18];
    const float* W4 = (const float*)d_in[19];
    const float* b4 = (const float*)d_in[20];
    float* wsf = (float*)d_ws;
    float* outf = (float*)d_out;

    if (ws_size < (size_t)WS_FLOATS * sizeof(float)) {
        fprintf(stderr, "kernel_launch: workspace too small (%zu < %zu)\n",
                ws_size, (size_t)WS_FLOATS * sizeof(float));
        return;
    }

    prep_kernel<<<dim3(1024), dim3(256), 0, stream>>>(W_hh, W_ih, wsf);

    (void)hipFuncSetAttribute((const void*)fused_kernel,
                              hipFuncAttributeMaxDynamicSharedMemorySize, LDS_BYTES);

    void* args[] = { &hiddens, &allys, &Wh, &bh, &Ws, &bs, &Wo, &bo,
                     &b_ih, &b_hh, &W1, &b1, &W2, &b2, &W3, &b3, &W4, &b4,
                     &wsf, &outf };
    hipError_t e = hipLaunchCooperativeKernel((void*)fused_kernel,
                                              dim3(NBLOCKS), dim3(NTHREADS),
                                              args, LDS_BYTES, stream);
    if (e != hipSuccess) {
        fprintf(stderr, "coop launch failed (%d); plain fallback\n", (int)e);
        (void)hipGetLastError();
        fused_kernel<<<dim3(NBLOCKS), dim3(NTHREADS), LDS_BYTES, stream>>>(
            hiddens, allys, Wh, bh, Ws, bs, Wo, bo, b_ih, b_hh,
            W1, b1, W2, b2, W3, b3, W4, b4, wsf, outf);
    }
}

// Round 3
// 2983.696 us; speedup vs baseline: 4.0784x; 1.7661x over previous
//
#include <hip/hip_runtime.h>
#include <cstdio>

#ifndef __has_builtin
#define __has_builtin(x) 0
#endif

// ---------------- problem constants ----------------
#define NB      256
#define NT      48
#define NS      512
#define KAHEAD  4
#define NTHREADS 1024
#define NBLOCKS  256
#define GSIZE    32      // blocks per group == rows per group

#define RSTRIDE  528     // floats per exchange row: 4 kq-blocks x 132 (128 data + 4 pad)
#define GROUPF   16896   // 32 * 528 floats per group
#define XSLOT    524     // x[512] scalar = kq3-block local offset 128

// ---------------- workspace layout (float offsets) ----------------
#define WS_D     0              // [256][528]
#define WS_X     135168         // [256][528]
#define WS_LH    270336         // [256][512]
#define WS_WHK   401408         // [128 k4][512 j][3 g][4 kk]   = 786432
#define WS_WIK   1187840        // [4 kq][33 t][512 j][3 g][4 kk] = 811008
#define WS_WHQ   1998848        // [128 k4][512 s][4 kk]        = 262144
#define WS_BAR   2260992        // 256 uints
#define WS_FLOATS 2261248

// ---------------- LDS layout (byte offsets) ----------------
#define L_BUF    0              // float [32][528]  67584
#define L_LSB    67584          // ushort [48][512] 49152
#define L_LH     116736         // float [512]
#define L_WO     118784         // float [512]
#define L_E      120832         // float [64]
#define L_ATT    121088         // float [64]
#define L_CP     121344         // float [512]
#define L_H1P    123392         // float [256*4]
#define L_H1S    127488         // float [256]
#define L_H2P    128512         // float [128*4]
#define L_H2S    130560         // float [128]
#define L_H3P    131072         // float [64*4]
#define LDS_BYTES 132096

typedef float f4 __attribute__((ext_vector_type(4)));

// ---------------- math helpers ----------------
__device__ __forceinline__ float frcp_(float x) {
#if __has_builtin(__builtin_amdgcn_rcpf)
    return __builtin_amdgcn_rcpf(x);
#else
    return 1.0f / x;
#endif
}
__device__ __forceinline__ float ftanh_(float x) {
    float e = __expf(2.0f * x);
    return 1.0f - 2.0f * frcp_(e + 1.0f);
}
__device__ __forceinline__ float fsig_(float x) { return frcp_(1.0f + __expf(-x)); }
__device__ __forceinline__ float lrelu_(float x) { return fmaxf(x, 0.01f * x); }
__device__ __forceinline__ unsigned short f2bf_(float x) {
    unsigned u = __float_as_uint(x);
    u += 0x7FFFu + ((u >> 16) & 1u);
    return (unsigned short)(u >> 16);
}
__device__ __forceinline__ float bf2f_(unsigned short b) {
    return __uint_as_float(((unsigned)b) << 16);
}

// ---------------- coherent (agent / MALL-level) access, vectorized ----------------
// Round 2 proved relaxed agent-scope atomics give correct cross-XCD exchange with
// no cache-invalidating fences. These asm forms are the dwordx4 equivalent (sc1).
__device__ __forceinline__ void cstore1(float* p, float v) {
    asm volatile("global_store_dword %0, %1, off sc1" :: "v"(p), "v"(v) : "memory");
}
__device__ __forceinline__ void cwait() {
    asm volatile("s_waitcnt vmcnt(0)" ::: "memory");
    __builtin_amdgcn_sched_barrier(0);
}

// stage 16896 floats (one group's exchange panel) global->LDS, linear, conflict-free
__device__ __forceinline__ void stageG(const float* __restrict__ gsrc,
                                       float* __restrict__ lds, int tid) {
    const float* p0 = gsrc + tid * 4;
    f4 a, b, c, d, e;
    asm volatile(
        "global_load_dwordx4 %0, %4, off sc1\n\t"
        "global_load_dwordx4 %1, %5, off sc1\n\t"
        "global_load_dwordx4 %2, %6, off sc1\n\t"
        "global_load_dwordx4 %3, %7, off sc1"
        : "=v"(a), "=v"(b), "=v"(c), "=v"(d)
        : "v"(p0), "v"(p0 + 4096), "v"(p0 + 8192), "v"(p0 + 12288));
    if (tid < 128) {
        asm volatile("global_load_dwordx4 %0, %1, off sc1"
                     : "=v"(e) : "v"(gsrc + 16384 + tid * 4));
    }
    cwait();
    *(f4*)(lds + tid * 4)         = a;
    *(f4*)(lds + 4096 + tid * 4)  = b;
    *(f4*)(lds + 8192 + tid * 4)  = c;
    *(f4*)(lds + 12288 + tid * 4) = d;
    if (tid < 128) *(f4*)(lds + 16384 + tid * 4) = e;
}

// Group barrier: monotonic counter, relaxed agent atomics (round-2 proven).
__device__ __forceinline__ void gbar(unsigned* bar, unsigned* epoch) {
    asm volatile("s_waitcnt vmcnt(0)" ::: "memory");   // drain our asm sc1 stores
    __syncthreads();
    if (threadIdx.x == 0) {
        *epoch += GSIZE;
        __hip_atomic_fetch_add(bar, 1u, __ATOMIC_RELAXED, __HIP_MEMORY_SCOPE_AGENT);
        unsigned target = *epoch;
        int guard = 0;
        while (__hip_atomic_load(bar, __ATOMIC_RELAXED, __HIP_MEMORY_SCOPE_AGENT) < target) {
#if __has_builtin(__builtin_amdgcn_s_sleep)
            __builtin_amdgcn_s_sleep(2);
#endif
            if (++guard > (1 << 22)) break;   // fail-safe: wrong answer, not a hang
        }
    }
    __syncthreads();
}

#define DOT4(acc, xv, wv) \
    acc = fmaf((xv).x, (wv).x, fmaf((xv).y, (wv).y, fmaf((xv).z, (wv).z, fmaf((xv).w, (wv).w, acc))))

__device__ __forceinline__ float redkq(float v) {
    v += __shfl_xor(v, 16, 64);
    v += __shfl_xor(v, 32, 64);
    return v;
}

// gh = d @ W_hh^T (2 rows x 3 gates, k split 4-way over lanes) [+ lh = d @ Wh]
template<bool DO_LH>
__device__ __forceinline__ void gemv_gh(const float* __restrict__ buf,
        const float* __restrict__ whk, const float* __restrict__ whq,
        int rp, int kq, int jg,
        float& g00, float& g01, float& g02, float& g10, float& g11, float& g12,
        float& l0, float& l1) {
    const float* a0 = buf + rp * 2 * RSTRIDE + kq * 132;
    const float* a1 = a0 + RSTRIDE;
    const float* wp = whk + ((long)(kq * 32) * 512 + jg) * 12;
    const float* wq = whq + ((long)(kq * 32) * 512 + jg) * 4;
    g00 = g01 = g02 = g10 = g11 = g12 = 0.f; l0 = 0.f; l1 = 0.f;
    #pragma unroll 2
    for (int k2 = 0; k2 < 32; ++k2) {
        f4 x0 = *(const f4*)(a0 + 4 * k2);
        f4 x1 = *(const f4*)(a1 + 4 * k2);
        f4 w0 = *(const f4*)(wp + 0);
        f4 w1 = *(const f4*)(wp + 4);
        f4 w2 = *(const f4*)(wp + 8);
        DOT4(g00, x0, w0); DOT4(g01, x0, w1); DOT4(g02, x0, w2);
        DOT4(g10, x1, w0); DOT4(g11, x1, w1); DOT4(g12, x1, w2);
        if (DO_LH) {
            f4 wl = *(const f4*)(wq);
            DOT4(l0, x0, wl); DOT4(l1, x1, wl);
            wq += 2048;
        }
        wp += 6144;
    }
    g00 = redkq(g00); g01 = redkq(g01); g02 = redkq(g02);
    g10 = redkq(g10); g11 = redkq(g11); g12 = redkq(g12);
    if (DO_LH) { l0 = redkq(l0); l1 = redkq(l1); }
}

// gi = x @ W_ih^T (33rd iteration carries the x[512] scalar; pads are zero)
__device__ __forceinline__ void gemv_gi(const float* __restrict__ buf,
        const float* __restrict__ wik, int rp, int kq, int jg,
        float& c00, float& c01, float& c02, float& c10, float& c11, float& c12) {
    const float* a0 = buf + rp * 2 * RSTRIDE + kq * 132;
    const float* a1 = a0 + RSTRIDE;
    const float* wp = wik + ((long)(kq * 33) * 512 + jg) * 12;
    c00 = c01 = c02 = c10 = c11 = c12 = 0.f;
    #pragma unroll 2
    for (int k2 = 0; k2 < 33; ++k2) {
        f4 x0 = *(const f4*)(a0 + 4 * k2);
        f4 x1 = *(const f4*)(a1 + 4 * k2);
        f4 w0 = *(const f4*)(wp + 0);
        f4 w1 = *(const f4*)(wp + 4);
        f4 w2 = *(const f4*)(wp + 8);
        DOT4(c00, x0, w0); DOT4(c01, x0, w1); DOT4(c02, x0, w2);
        DOT4(c10, x1, w0); DOT4(c11, x1, w1); DOT4(c12, x1, w2);
        wp += 6144;
    }
    c00 = redkq(c00); c01 = redkq(c01); c02 = redkq(c02);
    c10 = redkq(c10); c11 = redkq(c11); c12 = redkq(c12);
}

// ---------------- prep: weight packing + zeroing ----------------
__global__ void prep_kernel(const float* __restrict__ Whh,
                            const float* __restrict__ Wih,
                            const float* __restrict__ Wh,
                            float* __restrict__ ws) {
    long i = (long)blockIdx.x * blockDim.x + threadIdx.x;
    long stride = (long)gridDim.x * blockDim.x;
    // whk[p] : p = (k4*512 + j)*3 + g -> float4 of W_hh[(g*512+j)][k4*4 .. +3]
    for (long p = i; p < 196608; p += stride) {
        int gg = (int)(p % 3);
        long q = p / 3;
        int j = (int)(q & 511), k4 = (int)(q >> 9);
        f4 v = *(const f4*)(Whh + ((long)(gg * 512 + j)) * 512 + k4 * 4);
        *(f4*)(ws + WS_WHK + p * 4) = v;
    }
    // wik[p] : p = ((kq*33 + t)*512 + j)*3 + g ; t==32 -> zero pad except kq3/kk0 = k512 col
    for (long p = i; p < 202752; p += stride) {
        int gg = (int)(p % 3);
        long q = p / 3;
        int j = (int)(q & 511), kt = (int)(q >> 9);
        int kq = kt / 33, tt = kt - kq * 33;
        f4 v = {0.f, 0.f, 0.f, 0.f};
        const float* srow = Wih + ((long)(gg * 512 + j)) * 513;
        if (tt < 32) {
            int k = kq * 128 + tt * 4;
            v.x = srow[k]; v.y = srow[k + 1]; v.z = srow[k + 2]; v.w = srow[k + 3];
        } else if (kq == 3) {
            v.x = srow[512];
        }
        *(f4*)(ws + WS_WIK + p * 4) = v;
    }
    // whq[p] : p = k4*512 + s -> float4 of Wh[k4*4 .. +3][s]
    for (long p = i; p < 65536; p += stride) {
        int s = (int)(p & 511), k4 = (int)(p >> 9);
        f4 v = { Wh[(long)(k4 * 4 + 0) * 512 + s], Wh[(long)(k4 * 4 + 1) * 512 + s],
                 Wh[(long)(k4 * 4 + 2) * 512 + s], Wh[(long)(k4 * 4 + 3) * 512 + s] };
        *(f4*)(ws + WS_WHQ + p * 4) = v;
    }
    // zero d and x panels (incl. pads -> they must stay 0)
    for (long p = i; p < 270336; p += stride) ws[WS_D + p] = 0.0f;
    if (i < 256) ((unsigned*)(ws + WS_BAR))[i] = 0u;
}

// ---------------- main persistent cooperative kernel ----------------
__global__ void __launch_bounds__(NTHREADS, 4) fused_kernel(
        const float* __restrict__ hiddens, const float* __restrict__ allys,
        const float* __restrict__ Ws, const float* __restrict__ bs,
        const float* __restrict__ Wo, const float* __restrict__ bo,
        const float* __restrict__ bh,
        const float* __restrict__ b_ih, const float* __restrict__ b_hh,
        const float* __restrict__ W1, const float* __restrict__ b1,
        const float* __restrict__ W2, const float* __restrict__ b2,
        const float* __restrict__ W3, const float* __restrict__ b3,
        const float* __restrict__ W4, const float* __restrict__ b4,
        float* __restrict__ ws, float* __restrict__ out) {
    const int tid = threadIdx.x;
    const int bid = blockIdx.x;
    const int g = bid >> 5, cix = bid & 31, myb = bid;

    float* dw  = ws + WS_D;
    float* xw  = ws + WS_X;
    float* lhw = ws + WS_LH;
    const float* whk = ws + WS_WHK;
    const float* wik = ws + WS_WIK;
    const float* whq = ws + WS_WHQ;
    unsigned* bar = (unsigned*)(ws + WS_BAR) + (g << 5);
    unsigned epoch = 0;

    extern __shared__ char smem[];
    float*          buf   = (float*)(smem + L_BUF);
    unsigned short* lsb   = (unsigned short*)(smem + L_LSB);
    float*          lh_s  = (float*)(smem + L_LH);
    float*          wo_s  = (float*)(smem + L_WO);
    float*          e_s   = (float*)(smem + L_E);
    float*          att_s = (float*)(smem + L_ATT);
    float*          cp_s  = (float*)(smem + L_CP);
    float*          h1p   = (float*)(smem + L_H1P);
    float*          h1s   = (float*)(smem + L_H1S);
    float*          h2p   = (float*)(smem + L_H2P);
    float*          h2s   = (float*)(smem + L_H2S);
    float*          h3p   = (float*)(smem + L_H3P);

    const int rp = tid >> 6, lane = tid & 63, kq = lane >> 4, jj = lane & 15;
    const int jg = cix * 16 + jj;
    const int r0 = rp * 2, r1 = r0 + 1;
    const int sS = tid & 511, th = tid >> 9;
    const int jmap = ((jg >> 7) * 132) + (jg & 127);         // j -> padded row offset
    float* dRow0 = dw + (long)(g * GSIZE + r0) * RSTRIDE;    // this thread's d rows
    const float* gPanelD = dw + (long)g * GROUPF;
    const float* gPanelX = xw + (long)g * GROUPF;

    float hreg[24];   // hiddens[myb][th*24+q][sS]

    if (tid < NS) wo_s[tid] = Wo[tid];

    // ==== startup: ls = hiddens[myb] @ Ws + bs (bf16 in LDS); hiddens -> regs ====
    for (int ch = 0; ch < 2; ++ch) {
        __syncthreads();
        {   // stage 24 t-rows tight [24][512] (normal cached loads: read-only input)
            const float* src = hiddens + ((long)myb * NT + ch * 24) * NS;
            int idx = tid * 12;
            const f4* s4 = (const f4*)(src + idx);
            f4* d4 = (f4*)(buf + idx);
            d4[0] = s4[0]; d4[1] = s4[1]; d4[2] = s4[2];
        }
        __syncthreads();
        if (th == ch) {
            #pragma unroll
            for (int q = 0; q < 24; ++q) hreg[q] = buf[q * 512 + sS];
        }
        {
            const int tl = th * 12;
            float acc[12];
            #pragma unroll
            for (int q = 0; q < 12; ++q) acc[q] = 0.0f;
            for (int k = 0; k < NS; k += 4) {
                float w0 = Ws[(k + 0) * NS + sS];
                float w1 = Ws[(k + 1) * NS + sS];
                float w2 = Ws[(k + 2) * NS + sS];
                float w3 = Ws[(k + 3) * NS + sS];
                #pragma unroll
                for (int q = 0; q < 12; ++q) {
                    f4 h4 = *(const f4*)(buf + (tl + q) * 512 + k);
                    acc[q] = fmaf(h4.x, w0, fmaf(h4.y, w1, fmaf(h4.z, w2, fmaf(h4.w, w3, acc[q]))));
                }
            }
            float bsv = bs[sS];
            #pragma unroll
            for (int q = 0; q < 12; ++q)
                lsb[(ch * 24 + tl + q) * NS + sS] = f2bf_(acc[q] + bsv);
        }
    }
    __syncthreads();

    const float bo0 = bo[0];
    const float bhh0 = b_hh[jg], bhh1 = b_hh[512 + jg], bhh2 = b_hh[1024 + jg];
    const float bih0 = b_ih[jg], bih1 = b_ih[512 + jg], bih2 = b_ih[1024 + jg];
    const float bh_j = bh[jg];

    float g00, g01, g02, g10, g11, g12, l0, l1;

    // ================= time scan: 3 group barriers per step =================
    for (int t = 0; t < NT; ++t) {
        // ---- A: stage d_all; gh (regs) + lh column slice ----
        stageG(gPanelD, buf, tid);
        __syncthreads();
        gemv_gh<true>(buf, whk, whq, rp, kq, jg, g00, g01, g02, g10, g11, g12, l0, l1);
        g00 += bhh0; g01 += bhh1; g02 += bhh2;
        g10 += bhh0; g11 += bhh1; g12 += bhh2;
        if (kq == 0) {
            cstore1(lhw + (long)(g * GSIZE + r0) * NS + jg, l0 + bh_j);
            cstore1(lhw + (long)(g * GSIZE + r1) * NS + jg, l1 + bh_j);
        }
        gbar(bar, &epoch);

        // ---- B: attention for own row ----
        if (tid < 128) {
            f4 v;
            asm volatile("global_load_dwordx4 %0, %1, off sc1"
                         : "=v"(v) : "v"(lhw + (long)myb * NS + tid * 4));
            asm volatile("s_waitcnt vmcnt(0)" ::: "memory");
            __builtin_amdgcn_sched_barrier(0);
            *(f4*)(lh_s + tid * 4) = v;
        }
        if (tid == 0) cstore1(xw + (long)myb * RSTRIDE + XSLOT, allys[myb * NT + t]);
        __syncthreads();
        {   // e[t'] = sum_s wo[s]*tanh(lh[s]+ls[t'][s]) + bo
            const int wv = tid >> 6, ln = tid & 63;
            for (int q = 0; q < 3; ++q) {
                const int tt = wv * 3 + q;
                float p = 0.f;
                #pragma unroll
                for (int i2 = 0; i2 < 8; ++i2) {
                    int s = ln + (i2 << 6);
                    p = fmaf(wo_s[s], ftanh_(lh_s[s] + bf2f_(lsb[tt * NS + s])), p);
                }
                #pragma unroll
                for (int off = 32; off >= 1; off >>= 1) p += __shfl_xor(p, off, 64);
                if (ln == 0) e_s[tt] = p + bo0;
            }
        }
        __syncthreads();
        if (tid < 64) {
            float v = (tid < NT) ? e_s[tid] : -1e30f;
            float m = v;
            #pragma unroll
            for (int off = 32; off >= 1; off >>= 1) m = fmaxf(m, __shfl_xor(m, off, 64));
            float ex = (tid < NT) ? __expf(v - m) : 0.0f;
            float ssum = ex;
            #pragma unroll
            for (int off = 32; off >= 1; off >>= 1) ssum += __shfl_xor(ssum, off, 64);
            if (tid < NT) att_s[tid] = ex * frcp_(ssum);
        }
        __syncthreads();
        {   // c[s] = sum_t att[t]*hid[t][s]
            float p = 0.f;
            #pragma unroll
            for (int q = 0; q < 24; ++q) p = fmaf(att_s[th * 24 + q], hreg[q], p);
            if (th == 0) cp_s[sS] = p;
            __syncthreads();
            if (th == 1)
                cstore1(xw + (long)myb * RSTRIDE + ((sS >> 7) * 132) + (sS & 127), p + cp_s[sS]);
        }
        gbar(bar, &epoch);

        // ---- C: gi + GRU gates ----
        float hp0 = buf[r0 * RSTRIDE + jmap];
        float hp1 = buf[r1 * RSTRIDE + jmap];
        __syncthreads();
        stageG(gPanelX, buf, tid);
        __syncthreads();
        float c00, c01, c02, c10, c11, c12;
        gemv_gi(buf, wik, rp, kq, jg, c00, c01, c02, c10, c11, c12);
        if (kq == 0) {
            float rg = fsig_(c00 + bih0 + g00);
            float zg = fsig_(c01 + bih1 + g01);
            float ng = ftanh_(c02 + bih2 + rg * g02);
            cstore1(dRow0 + jmap, (1.f - zg) * ng + zg * hp0);
            rg = fsig_(c10 + bih0 + g10);
            zg = fsig_(c11 + bih1 + g11);
            ng = ftanh_(c12 + bih2 + rg * g12);
            cstore1(dRow0 + RSTRIDE + jmap, (1.f - zg) * ng + zg * hp1);
        }
        gbar(bar, &epoch);
    }

    // ================= k_wk_ahead head =================
    for (int kk = 0; kk < KAHEAD; ++kk) {
        {   // own d row -> lh_s (natural j order)
            float v = 0.f;
            if (tid < NS) {
                asm volatile("global_load_dword %0, %1, off sc1"
                             : "=v"(v) : "v"(dw + (long)myb * RSTRIDE + ((tid >> 7) * 132) + (tid & 127)));
            }
            asm volatile("s_waitcnt vmcnt(0)" ::: "memory");
            __builtin_amdgcn_sched_barrier(0);
            if (tid < NS) lh_s[tid] = v;
        }
        __syncthreads();
        {   // M1: 512 -> 256
            int n = tid & 255, q4 = tid >> 8;
            const float* av = lh_s + q4 * 128;
            const float* wp = W1 + (long)(q4 * 128) * 256 + n;
            float acc = 0.f;
            #pragma unroll 4
            for (int k2 = 0; k2 < 128; ++k2) { acc = fmaf(av[k2], wp[0], acc); wp += 256; }
            h1p[n * 4 + q4] = acc;
        }
        __syncthreads();
        if (tid < 256) {
            float v = h1p[tid * 4] + h1p[tid * 4 + 1] + h1p[tid * 4 + 2] + h1p[tid * 4 + 3];
            h1s[tid] = lrelu_(v + b1[tid]);
        }
        __syncthreads();
        if (tid < 512) {   // M2: 256 -> 128
            int n = tid & 127, q4 = tid >> 7;
            const float* av = h1s + q4 * 64;
            const float* wp = W2 + (long)(q4 * 64) * 128 + n;
            float acc = 0.f;
            #pragma unroll 4
            for (int k2 = 0; k2 < 64; ++k2) { acc = fmaf(av[k2], wp[0], acc); wp += 128; }
            h2p[n * 4 + q4] = acc;
        }
        __syncthreads();
        if (tid < 128) {
            float v = h2p[tid * 4] + h2p[tid * 4 + 1] + h2p[tid * 4 + 2] + h2p[tid * 4 + 3];
            h2s[tid] = lrelu_(v + b2[tid]);
        }
        __syncthreads();
        if (tid < 256) {   // M3: 128 -> 64
            int n = tid & 63, q4 = tid >> 6;
            const float* av = h2s + q4 * 32;
            const float* wp = W3 + (long)(q4 * 32) * 64 + n;
            float acc = 0.f;
            #pragma unroll 4
            for (int k2 = 0; k2 < 32; ++k2) { acc = fmaf(av[k2], wp[0], acc); wp += 64; }
            h3p[n * 4 + q4] = acc;
        }
        __syncthreads();
        if (tid < 64) {    // M3 epilogue + M4: 64 -> 1
            float v = h3p[tid * 4] + h3p[tid * 4 + 1] + h3p[tid * 4 + 2] + h3p[tid * 4 + 3];
            float h3v = lrelu_(v + b3[tid]);
            float p = h3v * W4[tid];
            #pragma unroll
            for (int off = 32; off >= 1; off >>= 1) p += __shfl_xor(p, off, 64);
            if (tid == 0) {
                float o = lrelu_(p + b4[0]);
                out[myb * KAHEAD + kk] = o;
                cstore1(xw + (long)myb * RSTRIDE + XSLOT, o);   // x = [c_last, out]
            }
        }
        if (kk < KAHEAD - 1) {
            gbar(bar, &epoch);
            // folded A+C (no attention)
            stageG(gPanelD, buf, tid);
            __syncthreads();
            gemv_gh<false>(buf, whk, whq, rp, kq, jg, g00, g01, g02, g10, g11, g12, l0, l1);
            g00 += bhh0; g01 += bhh1; g02 += bhh2;
            g10 += bhh0; g11 += bhh1; g12 += bhh2;
            float hp0 = buf[r0 * RSTRIDE + jmap];
            float hp1 = buf[r1 * RSTRIDE + jmap];
            __syncthreads();
            stageG(gPanelX, buf, tid);
            __syncthreads();
            float c00, c01, c02, c10, c11, c12;
            gemv_gi(buf, wik, rp, kq, jg, c00, c01, c02, c10, c11, c12);
            if (kq == 0) {
                float rg = fsig_(c00 + bih0 + g00);
                float zg = fsig_(c01 + bih1 + g01);
                float ng = ftanh_(c02 + bih2 + rg * g02);
                cstore1(dRow0 + jmap, (1.f - zg) * ng + zg * hp0);
                rg = fsig_(c10 + bih0 + g10);
                zg = fsig_(c11 + bih1 + g11);
                ng = ftanh_(c12 + bih2 + rg * g12);
                cstore1(dRow0 + RSTRIDE + jmap, (1.f - zg) * ng + zg * hp1);
            }
            gbar(bar, &epoch);
        }
    }
}

// ---------------- host ----------------
extern "C" void kernel_launch(void* const* d_in, const int* in_sizes, int n_in,
                              void* d_out, int out_size, void* d_ws, size_t ws_size,
                              hipStream_t stream) {
    const float* hiddens = (const float*)d_in[0];
    const float* allys   = (const float*)d_in[1];
    const float* Wh   = (const float*)d_in[3];
    const float* bh   = (const float*)d_in[4];
    const float* Ws   = (const float*)d_in[5];
    const float* bs   = (const float*)d_in[6];
    const float* Wo   = (const float*)d_in[7];
    const float* bo   = (const float*)d_in[8];
    const float* W_ih = (const float*)d_in[9];
    const float* W_hh = (const float*)d_in[10];
    const float* b_ih = (const float*)d_in[11];
    const float* b_hh = (const float*)d_in[12];
    const float* W1 = (const float*)d_in[13];
    const float* b1 = (const float*)d_in[14];
    const float* W2 = (const float*)d_in[15];
    const float* b2 = (const float*)d_in[16];
    const float* W3 = (const float*)d_in[17];
    const float* b3 = (const float*)d_in[18];
    const float* W4 = (const float*)d_in[19];
    const float* b4 = (const float*)d_in[20];
    float* wsf = (float*)d_ws;
    float* outf = (float*)d_out;

    if (ws_size < (size_t)WS_FLOATS * sizeof(float)) {
        fprintf(stderr, "kernel_launch: workspace too small (%zu < %zu)\n",
                ws_size, (size_t)WS_FLOATS * sizeof(float));
        return;
    }

    prep_kernel<<<dim3(2048), dim3(256), 0, stream>>>(W_hh, W_ih, Wh, wsf);

    (void)hipFuncSetAttribute((const void*)fused_kernel,
                              hipFuncAttributeMaxDynamicSharedMemorySize, LDS_BYTES);

    void* args[] = { &hiddens, &allys, &Ws, &bs, &Wo, &bo, &bh,
                     &b_ih, &b_hh, &W1, &b1, &W2, &b2, &W3, &b3, &W4, &b4,
                     &wsf, &outf };
    hipError_t e = hipLaunchCooperativeKernel((void*)fused_kernel,
                                              dim3(NBLOCKS), dim3(NTHREADS),
                                              args, LDS_BYTES, stream);
    if (e != hipSuccess) {
        fprintf(stderr, "coop launch failed (%d); plain fallback\n", (int)e);
        (void)hipGetLastError();
        fused_kernel<<<dim3(NBLOCKS), dim3(NTHREADS), LDS_BYTES, stream>>>(
            hiddens, allys, Ws, bs, Wo, bo, bh, b_ih, b_hh,
            W1, b1, W2, b2, W3, b3, W4, b4, wsf, outf);
    }
}

// Round 4
// 2100.076 us; speedup vs baseline: 5.7944x; 1.4208x over previous
//
#include <hip/hip_runtime.h>
#include <cstdio>

#ifndef __has_builtin
#define __has_builtin(x) 0
#endif

// ---------------- problem constants ----------------
#define NB      256
#define NT      48
#define NS      512
#define KAHEAD  4
#define NTHREADS 1024
#define NBLOCKS  256
#define GSIZE    32      // blocks per group == rows per group

#define RSTRIDE  528     // exchange row: 4 kq-blocks x 132 (128 data + 4 pad)
#define XSLOT    524     // x[512] scalar lives at panel col 524 (kq3, ko 128)
#define NKS      33      // 528 / 16 K-steps

// ---------------- workspace layout (float offsets) ----------------
#define WS_D     0              // [256][528] d exchange
#define WS_X     135168         // [256][528] x exchange
#define WS_LH    270336         // [256][512] lh exchange
#define WS_BAR   401408         // 256 uints
#define WS_WAH   401664         // whA hi: 1081344 ushort = 540672 fl
#define WS_WAL   942336         // whA lo
#define WS_WIH   1483008        // wiC hi: 811008 ushort = 405504 fl
#define WS_WIL   1888512        // wiC lo
#define WS_FLOATS 2294016       // 9.18 MB

// ---------------- LDS layout (byte offsets), total 145664 ----------------
#define L_XHI    0              // bf16 [32 rows][stride 1064B]  34048
#define L_XLO    34048          // bf16 panel lo                 34048
#define L_LSB    68096          // ushort [48][512] bf16 ls      49152
#define L_GH     117248         // float [3][32][17]              6528
#define L_GI     123776         // float [3][32][17]              6528
#define L_LH     130304         // float [512]
#define L_WO     132352         // float [512]
#define L_E      134400         // float [64]
#define L_ATT    134656         // float [64]
#define L_CP     134912         // float [512]
#define L_H1P    136960         // float [256*4]
#define L_H1S    141056         // float [256]
#define L_H2P    142080         // float [128*4]
#define L_H2S    144128         // float [128]
#define L_H3P    144640         // float [64*4]
#define LDS_BYTES 145664

#define XROWB    1064           // bf16 panel row stride in bytes

typedef float  f4v __attribute__((ext_vector_type(4)));
typedef short  s4v __attribute__((ext_vector_type(4)));
typedef unsigned short u4v __attribute__((ext_vector_type(4)));

// ---------------- MFMA 16x16x16 bf16 ----------------
#if __has_builtin(__builtin_amdgcn_mfma_f32_16x16x16bf16_1k)
__device__ __forceinline__ f4v MFMA16(s4v a, s4v b, f4v c) {
    return __builtin_amdgcn_mfma_f32_16x16x16bf16_1k(a, b, c, 0, 0, 0);
}
#else
// layout-robust fallback: zero-padded halves of the verified 16x16x32 op
typedef short s8v __attribute__((ext_vector_type(8)));
__device__ __forceinline__ f4v MFMA16(s4v a, s4v b, f4v c) {
    s8v A = { a[0], a[1], a[2], a[3], 0, 0, 0, 0 };
    s8v B = { b[0], b[1], b[2], b[3], 0, 0, 0, 0 };
    return __builtin_amdgcn_mfma_f32_16x16x32_bf16(A, B, c, 0, 0, 0);
}
#endif

// ---------------- math helpers ----------------
__device__ __forceinline__ float frcp_(float x) {
#if __has_builtin(__builtin_amdgcn_rcpf)
    return __builtin_amdgcn_rcpf(x);
#else
    return 1.0f / x;
#endif
}
__device__ __forceinline__ float ftanh_(float x) {
    float e = __expf(2.0f * x);
    return 1.0f - 2.0f * frcp_(e + 1.0f);
}
__device__ __forceinline__ float fsig_(float x) { return frcp_(1.0f + __expf(-x)); }
__device__ __forceinline__ float lrelu_(float x) { return fmaxf(x, 0.01f * x); }
__device__ __forceinline__ unsigned short rne16_(unsigned u) {
    return (unsigned short)((u + 0x7FFFu + ((u >> 16) & 1u)) >> 16);
}
__device__ __forceinline__ float bf2f_(unsigned short b) {
    return __uint_as_float(((unsigned)b) << 16);
}
__host__ __device__ __forceinline__ void split2_(float v, unsigned short& hi, unsigned short& lo) {
    unsigned u = __float_as_uint(v);
    unsigned short h = (unsigned short)((u + 0x7FFFu + ((u >> 16) & 1u)) >> 16);
    float hf = __uint_as_float(((unsigned)h) << 16);
    float lof = v - hf;
    unsigned ul = __float_as_uint(lof);
    hi = h;
    lo = (unsigned short)((ul + 0x7FFFu + ((ul >> 16) & 1u)) >> 16);
}

// ---------------- coherent (MALL-level) access (round-2/3 proven) ----------------
__device__ __forceinline__ void cstore1(float* p, float v) {
    asm volatile("global_store_dword %0, %1, off sc1" :: "v"(p), "v"(v) : "memory");
}
__device__ __forceinline__ f4v cload4(const float* p) {
    f4v v;
    asm volatile("global_load_dwordx4 %0, %1, off sc1" : "=v"(v) : "v"(p));
    return v;
}
__device__ __forceinline__ float cload1(const float* p) {
    float v;
    asm volatile("global_load_dword %0, %1, off sc1" : "=v"(v) : "v"(p));
    return v;
}
__device__ __forceinline__ void cwait() {
    asm volatile("s_waitcnt vmcnt(0)" ::: "memory");
    __builtin_amdgcn_sched_barrier(0);
}

// Group barrier: monotonic counter, relaxed agent atomics (proven r2/r3).
__device__ __forceinline__ void gbar(unsigned* bar, unsigned* epoch) {
    asm volatile("s_waitcnt vmcnt(0)" ::: "memory");
    __syncthreads();
    if (threadIdx.x == 0) {
        *epoch += GSIZE;
        __hip_atomic_fetch_add(bar, 1u, __ATOMIC_RELAXED, __HIP_MEMORY_SCOPE_AGENT);
        unsigned target = *epoch;
        int guard = 0;
        while (__hip_atomic_load(bar, __ATOMIC_RELAXED, __HIP_MEMORY_SCOPE_AGENT) < target) {
#if __has_builtin(__builtin_amdgcn_s_sleep)
            __builtin_amdgcn_s_sleep(2);
#endif
            if (++guard > (1 << 22)) break;   // fail-safe: wrong answer, not a hang
        }
    }
    __syncthreads();
}

// ---------------- staging: exchange fp32 panel -> LDS bf16 hi/lo ----------------
__device__ __forceinline__ void cvtStore_(char* hiB, char* loB, int idx, f4v v) {
    unsigned row = (unsigned)idx / 528u;
    unsigned col = (unsigned)idx - row * 528u;
    u4v h, l;
    #pragma unroll
    for (int i = 0; i < 4; ++i) {
        unsigned short hh, ll;
        split2_(v[i], hh, ll);
        h[i] = hh; l[i] = ll;
    }
    *(u4v*)(hiB + row * XROWB + col * 2) = h;
    *(u4v*)(loB + row * XROWB + col * 2) = l;
}

__device__ __forceinline__ void stagePanel(const float* __restrict__ gsrc,
                                           char* __restrict__ hiB,
                                           char* __restrict__ loB, int tid) {
    f4v v0 = cload4(gsrc + tid * 4);
    f4v v1 = cload4(gsrc + 4096 + tid * 4);
    f4v v2 = cload4(gsrc + 8192 + tid * 4);
    f4v v3 = cload4(gsrc + 12288 + tid * 4);
    f4v v4 = {0.f, 0.f, 0.f, 0.f};
    if (tid < 128) v4 = cload4(gsrc + 16384 + tid * 4);
    cwait();
    cvtStore_(hiB, loB, tid * 4, v0);
    cvtStore_(hiB, loB, 4096 + tid * 4, v1);
    cvtStore_(hiB, loB, 8192 + tid * 4, v2);
    cvtStore_(hiB, loB, 12288 + tid * 4, v3);
    if (tid < 128) cvtStore_(hiB, loB, 16384 + tid * 4, v4);
}

// ---------------- MFMA GEMM stages ----------------
// Stage A: C[32x64] = D[32x528] @ W; nt0 = lh (-> exchange), nt1..3 = gh gates (-> gh_s)
__device__ __forceinline__ void gemmA(const char* smem, const unsigned short* BH,
        const unsigned short* BL, int cix, int g, int tid, float* ghs,
        float* lhw, const float* bh, const float* bhh, bool doLH) {
    const int w = tid >> 6;
    if (w >= 8) return;
    const int l = tid & 63, mt = w & 1, nt = w >> 1;
    const char* A  = smem + L_XHI + (mt * 16 + (l & 15)) * XROWB + ((l >> 4) << 3);
    const char* Al = A + (L_XLO - L_XHI);
    const int bbase = ((cix * 4 + nt) * NKS) * 256 + (l << 2);
    f4v acc = {0.f, 0.f, 0.f, 0.f};
    #pragma unroll 3
    for (int ks = 0; ks < NKS; ++ks) {
        s4v ah = *(const s4v*)(A + ks * 32);
        s4v al = *(const s4v*)(Al + ks * 32);
        s4v bhv = *(const s4v*)(BH + bbase + ks * 256);
        s4v blv = *(const s4v*)(BL + bbase + ks * 256);
        acc = MFMA16(ah, bhv, acc);
        acc = MFMA16(al, bhv, acc);
        acc = MFMA16(ah, blv, acc);
    }
    const int jgl = cix * 16 + (l & 15);
    const int rowL = mt * 16 + ((l >> 4) << 2);
    if (nt == 0) {
        if (doLH) {
            float b = bh[jgl];
            #pragma unroll
            for (int r = 0; r < 4; ++r)
                cstore1(lhw + (long)(g * 32 + rowL + r) * NS + jgl, acc[r] + b);
        }
    } else {
        float b = bhh[(nt - 1) * 512 + jgl];
        #pragma unroll
        for (int r = 0; r < 4; ++r)
            ghs[(nt - 1) * 544 + (rowL + r) * 17 + (l & 15)] = acc[r] + b;
    }
}

// Stage C GEMM: gi gates -> gi_s
__device__ __forceinline__ void gemmC(const char* smem, const unsigned short* BH,
        const unsigned short* BL, int cix, int tid, float* gis, const float* bih) {
    const int w = tid >> 6;
    if (w >= 6) return;
    const int l = tid & 63, mt = w & 1, nt = w >> 1;
    const char* A  = smem + L_XHI + (mt * 16 + (l & 15)) * XROWB + ((l >> 4) << 3);
    const char* Al = A + (L_XLO - L_XHI);
    const int bbase = ((cix * 3 + nt) * NKS) * 256 + (l << 2);
    f4v acc = {0.f, 0.f, 0.f, 0.f};
    #pragma unroll 3
    for (int ks = 0; ks < NKS; ++ks) {
        s4v ah = *(const s4v*)(A + ks * 32);
        s4v al = *(const s4v*)(Al + ks * 32);
        s4v bhv = *(const s4v*)(BH + bbase + ks * 256);
        s4v blv = *(const s4v*)(BL + bbase + ks * 256);
        acc = MFMA16(ah, bhv, acc);
        acc = MFMA16(al, bhv, acc);
        acc = MFMA16(ah, blv, acc);
    }
    const int jgl = cix * 16 + (l & 15);
    const int rowL = mt * 16 + ((l >> 4) << 2);
    float b = bih[nt * 512 + jgl];
    #pragma unroll
    for (int r = 0; r < 4; ++r)
        gis[nt * 544 + (rowL + r) * 17 + (l & 15)] = acc[r] + b;
}

// ---------------- prep: fragment packing + zeroing ----------------
__global__ void prep_kernel(const float* __restrict__ Whh,
                            const float* __restrict__ Wih,
                            const float* __restrict__ Wh,
                            float* __restrict__ ws) {
    long i = (long)blockIdx.x * blockDim.x + threadIdx.x;
    long stride = (long)gridDim.x * blockDim.x;
    unsigned short* waH = (unsigned short*)(ws + WS_WAH);
    unsigned short* waL = (unsigned short*)(ws + WS_WAL);
    unsigned short* wiH = (unsigned short*)(ws + WS_WIH);
    unsigned short* wiL = (unsigned short*)(ws + WS_WIL);

    // whA: p = ((cix*4+nt)*33 + ks)*64 + l ; 270336 groups
    for (long p = i; p < 270336; p += stride) {
        int l = (int)(p & 63);
        int t = (int)(p >> 6);
        int ks = t % NKS, u = t / NKS;
        int nt = u & 3, cix = u >> 2;
        int jg = cix * 16 + (l & 15);
        #pragma unroll
        for (int e = 0; e < 4; ++e) {
            int pc = ks * 16 + ((l >> 4) << 2) + e;
            int kq = pc / 132, ko = pc - kq * 132;
            float wv = 0.f;
            if (ko < 128) {
                int k = kq * 128 + ko;
                wv = (nt == 0) ? Wh[(long)k * 512 + jg]
                               : Whh[((long)((nt - 1) * 512 + jg)) * 512 + k];
            }
            unsigned short hh, ll;
            split2_(wv, hh, ll);
            waH[p * 4 + e] = hh; waL[p * 4 + e] = ll;
        }
    }
    // wiC: p = ((cix*3+nt)*33 + ks)*64 + l ; 202752 groups
    for (long p = i; p < 202752; p += stride) {
        int l = (int)(p & 63);
        int t = (int)(p >> 6);
        int ks = t % NKS, u = t / NKS;
        int nt = u % 3, cix = u / 3;
        int jg = cix * 16 + (l & 15);
        #pragma unroll
        for (int e = 0; e < 4; ++e) {
            int pc = ks * 16 + ((l >> 4) << 2) + e;
            int kq = pc / 132, ko = pc - kq * 132;
            float wv = 0.f;
            int k = -1;
            if (ko < 128) k = kq * 128 + ko;
            else if (pc == XSLOT) k = 512;
            if (k >= 0) wv = Wih[((long)(nt * 512 + jg)) * 513 + k];
            unsigned short hh, ll;
            split2_(wv, hh, ll);
            wiH[p * 4 + e] = hh; wiL[p * 4 + e] = ll;
        }
    }
    // zero d and x exchange panels (pads must stay zero)
    for (long p = i; p < 270336; p += stride) ws[WS_D + p] = 0.0f;
    if (i < 256) ((unsigned*)(ws + WS_BAR))[i] = 0u;
}

// ---------------- main persistent cooperative kernel ----------------
__global__ void __launch_bounds__(NTHREADS, 4) fused_kernel(
        const float* __restrict__ hiddens, const float* __restrict__ allys,
        const float* __restrict__ Ws, const float* __restrict__ bs,
        const float* __restrict__ Wo, const float* __restrict__ bo,
        const float* __restrict__ bh,
        const float* __restrict__ b_ih, const float* __restrict__ b_hh,
        const float* __restrict__ W1, const float* __restrict__ b1,
        const float* __restrict__ W2, const float* __restrict__ b2,
        const float* __restrict__ W3, const float* __restrict__ b3,
        const float* __restrict__ W4, const float* __restrict__ b4,
        float* __restrict__ ws, float* __restrict__ out) {
    const int tid = threadIdx.x;
    const int bid = blockIdx.x;
    const int g = bid >> 5, cix = bid & 31, myb = bid;

    float* dw  = ws + WS_D;
    float* xw  = ws + WS_X;
    float* lhw = ws + WS_LH;
    const unsigned short* waH = (const unsigned short*)(ws + WS_WAH);
    const unsigned short* waL = (const unsigned short*)(ws + WS_WAL);
    const unsigned short* wiH = (const unsigned short*)(ws + WS_WIH);
    const unsigned short* wiL = (const unsigned short*)(ws + WS_WIL);
    unsigned* bar = (unsigned*)(ws + WS_BAR) + (g << 5);
    unsigned epoch = 0;

    extern __shared__ char smem[];
    char*           xhi   = smem + L_XHI;
    char*           xlo   = smem + L_XLO;
    unsigned short* lsb   = (unsigned short*)(smem + L_LSB);
    float*          ghs   = (float*)(smem + L_GH);
    float*          gis   = (float*)(smem + L_GI);
    float*          lh_s  = (float*)(smem + L_LH);
    float*          wo_s  = (float*)(smem + L_WO);
    float*          e_s   = (float*)(smem + L_E);
    float*          att_s = (float*)(smem + L_ATT);
    float*          cp_s  = (float*)(smem + L_CP);
    float*          h1p   = (float*)(smem + L_H1P);
    float*          h1s   = (float*)(smem + L_H1S);
    float*          h2p   = (float*)(smem + L_H2P);
    float*          h2s   = (float*)(smem + L_H2S);
    float*          h3p   = (float*)(smem + L_H3P);

    const int sS = tid & 511, th = tid >> 9;
    const int rowE = tid >> 4, jE = tid & 15;                 // epilogue map (tid<512)
    const int jgE = cix * 16 + jE;
    const int jmapE = ((jgE >> 7) * 132) + (jgE & 127);
    const float* gPanelD = dw + (long)g * GSIZE * RSTRIDE;
    const float* gPanelX = xw + (long)g * GSIZE * RSTRIDE;

    float hreg[24];   // hiddens[myb][th*24+q][sS]

    if (tid < NS) wo_s[tid] = Wo[tid];

    // ==== startup: ls = hiddens[myb] @ Ws + bs (bf16 in LDS); hiddens -> regs ====
    {
        float* scratch = (float*)(smem + L_XHI);   // 48KB fp32 scratch (pre-GEMM)
        for (int ch = 0; ch < 2; ++ch) {
            __syncthreads();
            {
                const float* src = hiddens + ((long)myb * NT + ch * 24) * NS;
                int idx = tid * 12;
                const f4v* s4 = (const f4v*)(src + idx);
                f4v* d4 = (f4v*)(scratch + idx);
                d4[0] = s4[0]; d4[1] = s4[1]; d4[2] = s4[2];
            }
            __syncthreads();
            if (th == ch) {
                #pragma unroll
                for (int q = 0; q < 24; ++q) hreg[q] = scratch[q * 512 + sS];
            }
            {
                const int tl = th * 12;
                float acc[12];
                #pragma unroll
                for (int q = 0; q < 12; ++q) acc[q] = 0.0f;
                for (int k = 0; k < NS; k += 4) {
                    float w0 = Ws[(k + 0) * NS + sS];
                    float w1 = Ws[(k + 1) * NS + sS];
                    float w2 = Ws[(k + 2) * NS + sS];
                    float w3 = Ws[(k + 3) * NS + sS];
                    #pragma unroll
                    for (int q = 0; q < 12; ++q) {
                        f4v h4 = *(const f4v*)(scratch + (tl + q) * 512 + k);
                        acc[q] = fmaf(h4.x, w0, fmaf(h4.y, w1, fmaf(h4.z, w2, fmaf(h4.w, w3, acc[q]))));
                    }
                }
                float bsv = bs[sS];
                #pragma unroll
                for (int q = 0; q < 12; ++q)
                    lsb[(ch * 24 + tl + q) * NS + sS] = rne16_(__float_as_uint(acc[q] + bsv));
            }
        }
    }
    __syncthreads();

    const float bo0 = bo[0];

    // ================= time scan: 3 group barriers per step =================
    for (int t = 0; t < NT; ++t) {
        // ---- A: stage d -> bf16 panels; MFMA gh + lh ----
        stagePanel(gPanelD, xhi, xlo, tid);
        __syncthreads();
        gemmA(smem, waH, waL, cix, g, tid, ghs, lhw, bh, b_hh, true);
        gbar(bar, &epoch);

        // ---- B: attention for own row ----
        if (tid < 128) {
            f4v v = cload4(lhw + (long)myb * NS + tid * 4);
            cwait();
            *(f4v*)(lh_s + tid * 4) = v;
        }
        if (tid == 0) cstore1(xw + (long)myb * RSTRIDE + XSLOT, allys[myb * NT + t]);
        __syncthreads();
        {
            const int wv = tid >> 6, ln = tid & 63;
            for (int q = 0; q < 3; ++q) {
                const int tt = wv * 3 + q;
                float p = 0.f;
                #pragma unroll
                for (int i2 = 0; i2 < 8; ++i2) {
                    int s = ln + (i2 << 6);
                    p = fmaf(wo_s[s], ftanh_(lh_s[s] + bf2f_(lsb[tt * NS + s])), p);
                }
                #pragma unroll
                for (int off = 32; off >= 1; off >>= 1) p += __shfl_xor(p, off, 64);
                if (ln == 0) e_s[tt] = p + bo0;
            }
        }
        __syncthreads();
        if (tid < 64) {
            float v = (tid < NT) ? e_s[tid] : -1e30f;
            float m = v;
            #pragma unroll
            for (int off = 32; off >= 1; off >>= 1) m = fmaxf(m, __shfl_xor(m, off, 64));
            float ex = (tid < NT) ? __expf(v - m) : 0.0f;
            float ssum = ex;
            #pragma unroll
            for (int off = 32; off >= 1; off >>= 1) ssum += __shfl_xor(ssum, off, 64);
            if (tid < NT) att_s[tid] = ex * frcp_(ssum);
        }
        __syncthreads();
        {
            float p = 0.f;
            #pragma unroll
            for (int q = 0; q < 24; ++q) p = fmaf(att_s[th * 24 + q], hreg[q], p);
            if (th == 0) cp_s[sS] = p;
            __syncthreads();
            if (th == 1)
                cstore1(xw + (long)myb * RSTRIDE + ((sS >> 7) * 132) + (sS & 127), p + cp_s[sS]);
        }
        gbar(bar, &epoch);

        // ---- C: gi MFMA + GRU gates ----
        float hp = 0.f;
        if (tid < 512) hp = cload1(dw + (long)(g * 32 + rowE) * RSTRIDE + jmapE);
        stagePanel(gPanelX, xhi, xlo, tid);
        __syncthreads();
        gemmC(smem, wiH, wiL, cix, tid, gis, b_ih);
        __syncthreads();
        cwait();
        if (tid < 512) {
            float gr = gis[rowE * 17 + jE]        + ghs[rowE * 17 + jE];
            float gz = gis[544 + rowE * 17 + jE]  + ghs[544 + rowE * 17 + jE];
            float gni = gis[1088 + rowE * 17 + jE];
            float gnh = ghs[1088 + rowE * 17 + jE];
            float rg = fsig_(gr);
            float zg = fsig_(gz);
            float ng = ftanh_(gni + rg * gnh);
            cstore1(dw + (long)(g * 32 + rowE) * RSTRIDE + jmapE, (1.f - zg) * ng + zg * hp);
        }
        gbar(bar, &epoch);
    }

    // ================= k_wk_ahead head =================
    for (int kk = 0; kk < KAHEAD; ++kk) {
        {
            float v = 0.f;
            if (tid < NS) v = cload1(dw + (long)myb * RSTRIDE + ((tid >> 7) * 132) + (tid & 127));
            cwait();
            if (tid < NS) lh_s[tid] = v;
        }
        __syncthreads();
        {   // M1: 512 -> 256
            int n = tid & 255, q4 = tid >> 8;
            const float* av = lh_s + q4 * 128;
            const float* wp = W1 + (long)(q4 * 128) * 256 + n;
            float acc = 0.f;
            #pragma unroll 4
            for (int k2 = 0; k2 < 128; ++k2) { acc = fmaf(av[k2], wp[0], acc); wp += 256; }
            h1p[n * 4 + q4] = acc;
        }
        __syncthreads();
        if (tid < 256) {
            float v = h1p[tid * 4] + h1p[tid * 4 + 1] + h1p[tid * 4 + 2] + h1p[tid * 4 + 3];
            h1s[tid] = lrelu_(v + b1[tid]);
        }
        __syncthreads();
        if (tid < 512) {   // M2: 256 -> 128
            int n = tid & 127, q4 = tid >> 7;
            const float* av = h1s + q4 * 64;
            const float* wp = W2 + (long)(q4 * 64) * 128 + n;
            float acc = 0.f;
            #pragma unroll 4
            for (int k2 = 0; k2 < 64; ++k2) { acc = fmaf(av[k2], wp[0], acc); wp += 128; }
            h2p[n * 4 + q4] = acc;
        }
        __syncthreads();
        if (tid < 128) {
            float v = h2p[tid * 4] + h2p[tid * 4 + 1] + h2p[tid * 4 + 2] + h2p[tid * 4 + 3];
            h2s[tid] = lrelu_(v + b2[tid]);
        }
        __syncthreads();
        if (tid < 256) {   // M3: 128 -> 64
            int n = tid & 63, q4 = tid >> 6;
            const float* av = h2s + q4 * 32;
            const float* wp = W3 + (long)(q4 * 32) * 64 + n;
            float acc = 0.f;
            #pragma unroll 4
            for (int k2 = 0; k2 < 32; ++k2) { acc = fmaf(av[k2], wp[0], acc); wp += 64; }
            h3p[n * 4 + q4] = acc;
        }
        __syncthreads();
        if (tid < 64) {    // M3 epilogue + M4: 64 -> 1
            float v = h3p[tid * 4] + h3p[tid * 4 + 1] + h3p[tid * 4 + 2] + h3p[tid * 4 + 3];
            float h3v = lrelu_(v + b3[tid]);
            float p = h3v * W4[tid];
            #pragma unroll
            for (int off = 32; off >= 1; off >>= 1) p += __shfl_xor(p, off, 64);
            if (tid == 0) {
                float o = lrelu_(p + b4[0]);
                out[myb * KAHEAD + kk] = o;
                cstore1(xw + (long)myb * RSTRIDE + XSLOT, o);   // x = [c_last, out]
            }
        }
        if (kk < KAHEAD - 1) {
            gbar(bar, &epoch);
            float hp = 0.f;
            if (tid < 512) hp = cload1(dw + (long)(g * 32 + rowE) * RSTRIDE + jmapE);
            stagePanel(gPanelD, xhi, xlo, tid);
            __syncthreads();
            gemmA(smem, waH, waL, cix, g, tid, ghs, lhw, bh, b_hh, false);
            __syncthreads();
            stagePanel(gPanelX, xhi, xlo, tid);
            __syncthreads();
            gemmC(smem, wiH, wiL, cix, tid, gis, b_ih);
            __syncthreads();
            cwait();
            if (tid < 512) {
                float gr = gis[rowE * 17 + jE]        + ghs[rowE * 17 + jE];
                float gz = gis[544 + rowE * 17 + jE]  + ghs[544 + rowE * 17 + jE];
                float gni = gis[1088 + rowE * 17 + jE];
                float gnh = ghs[1088 + rowE * 17 + jE];
                float rg = fsig_(gr);
                float zg = fsig_(gz);
                float ng = ftanh_(gni + rg * gnh);
                cstore1(dw + (long)(g * 32 + rowE) * RSTRIDE + jmapE, (1.f - zg) * ng + zg * hp);
            }
            gbar(bar, &epoch);
        }
    }
}

// ---------------- host ----------------
extern "C" void kernel_launch(void* const* d_in, const int* in_sizes, int n_in,
                              void* d_out, int out_size, void* d_ws, size_t ws_size,
                              hipStream_t stream) {
    const float* hiddens = (const float*)d_in[0];
    const float* allys   = (const float*)d_in[1];
    const float* Wh   = (const float*)d_in[3];
    const float* bh   = (const float*)d_in[4];
    const float* Ws   = (const float*)d_in[5];
    const float* bs   = (const float*)d_in[6];
    const float* Wo   = (const float*)d_in[7];
    const float* bo   = (const float*)d_in[8];
    const float* W_ih = (const float*)d_in[9];
    const float* W_hh = (const float*)d_in[10];
    const float* b_ih = (const float*)d_in[11];
    const float* b_hh = (const float*)d_in[12];
    const float* W1 = (const float*)d_in[13];
    const float* b1 = (const float*)d_in[14];
    const float* W2 = (const float*)d_in[15];
    const float* b2 = (const float*)d_in[16];
    const float* W3 = (const float*)d_in[17];
    const float* b3 = (const float*)d_in[18];
    const float* W4 = (const float*)d_in[19];
    const float* b4 = (const float*)d_in[20];
    float* wsf = (float*)d_ws;
    float* outf = (float*)d_out;

    if (ws_size < (size_t)WS_FLOATS * sizeof(float)) {
        fprintf(stderr, "kernel_launch: workspace too small (%zu < %zu)\n",
                ws_size, (size_t)WS_FLOATS * sizeof(float));
        return;
    }

    prep_kernel<<<dim3(2048), dim3(256), 0, stream>>>(W_hh, W_ih, Wh, wsf);

    (void)hipFuncSetAttribute((const void*)fused_kernel,
                              hipFuncAttributeMaxDynamicSharedMemorySize, LDS_BYTES);

    void* args[] = { &hiddens, &allys, &Ws, &bs, &Wo, &bo, &bh,
                     &b_ih, &b_hh, &W1, &b1, &W2, &b2, &W3, &b3, &W4, &b4,
                     &wsf, &outf };
    hipError_t e = hipLaunchCooperativeKernel((void*)fused_kernel,
                                              dim3(NBLOCKS), dim3(NTHREADS),
                                              args, LDS_BYTES, stream);
    if (e != hipSuccess) {
        fprintf(stderr, "coop launch failed (%d); plain fallback\n", (int)e);
        (void)hipGetLastError();
        fused_kernel<<<dim3(NBLOCKS), dim3(NTHREADS), LDS_BYTES, stream>>>(
            hiddens, allys, Ws, bs, Wo, bo, bh, b_ih, b_hh,
            W1, b1, W2, b2, W3, b3, W4, b4, wsf, outf);
    }
}